// Round 3
// baseline (550.547 us; speedup 1.0000x reference)
//
#include <hip/hip_runtime.h>
#include <hip/hip_cooperative_groups.h>
#include <cmath>

namespace cg = cooperative_groups;

#define R_TOT 4096   // B*S rows
#define HID   768
#define NHEAD 12
#define HDIM  64
#define SEQ   512
#define BATCH 8
#define GRID_N 768   // 3 blocks/CU x 256 CU — co-resident for grid.sync

typedef int   v4i  __attribute__((ext_vector_type(4)));
typedef float v4f  __attribute__((ext_vector_type(4)));
typedef _Float16 half8 __attribute__((ext_vector_type(8)));
typedef _Float16 half4v __attribute__((ext_vector_type(4)));

// Direct global->LDS DMA, 16B per lane. HW semantics (m104/m108): dest =
// readfirstlane(ldsptr) + lane*16 — pass the wave-uniform chunk base.
__device__ __forceinline__ void gl_lds16(const signed char* g, signed char* l) {
  __builtin_amdgcn_global_load_lds(
      (const __attribute__((address_space(1))) void*)g,
      (__attribute__((address_space(3))) void*)l, 16, 0, 0);
}

// ---------------- PLA coefficients (host, replicates np.polyfit in f64) ----
struct PlaConsts { float m[12]; float c[12]; float b[13]; };

static PlaConsts build_pla() {
  PlaConsts pc;
  const int NPTS = 1001;
  static double xs[NPTS], ys[NPTS];
  const double step = 10.0 / 1000.0;
  for (int j = 0; j < NPTS; ++j) xs[j] = (double)j * step + (-10.0);
  xs[NPTS - 1] = 0.0;
  for (int j = 0; j < NPTS; ++j) ys[j] = std::exp(xs[j]);
  double bnd[13];
  const double step2 = 10.0 / 12.0;
  for (int k = 0; k < 13; ++k) bnd[k] = (double)k * step2 + (-10.0);
  bnd[12] = 0.0;
  for (int i = 0; i < 12; ++i) {
    const double a = bnd[i], bb = bnd[i + 1];
    double sx = 0, sy = 0; int n = 0;
    for (int j = 0; j < NPTS; ++j)
      if (xs[j] >= a && xs[j] <= bb) { sx += xs[j]; sy += ys[j]; ++n; }
    const double xm = sx / n, ym = sy / n;
    double sxx = 0, sxy = 0;
    for (int j = 0; j < NPTS; ++j)
      if (xs[j] >= a && xs[j] <= bb) {
        const double dx = xs[j] - xm;
        sxx += dx * dx; sxy += dx * (ys[j] - ym);
      }
    const double m = sxy / sxx;
    pc.m[i] = (float)m;
    pc.c[i] = (float)(ym - m * xm);
  }
  for (int k = 0; k < 13; ++k) pc.b[k] = (float)bnd[k];
  return pc;
}
static const PlaConsts g_pla = build_pla();

// ---------------- per-row abs-max int8 quantization (768 cols) -------------
__device__ __forceinline__ void quant_row_wave(const float* __restrict__ x,
                                               signed char* __restrict__ qrow,
                                               float* __restrict__ srow) {
  const int lane = threadIdx.x & 63;
  const float4* x4 = (const float4*)x;
  const float4 a = x4[lane];
  const float4 b = x4[lane + 64];
  const float4 c = x4[lane + 128];
  float m = fmaxf(fmaxf(fabsf(a.x), fabsf(a.y)), fmaxf(fabsf(a.z), fabsf(a.w)));
  m = fmaxf(m, fmaxf(fmaxf(fabsf(b.x), fabsf(b.y)), fmaxf(fabsf(b.z), fabsf(b.w))));
  m = fmaxf(m, fmaxf(fmaxf(fabsf(c.x), fabsf(c.y)), fmaxf(fabsf(c.z), fabsf(c.w))));
  #pragma unroll
  for (int off = 32; off; off >>= 1) m = fmaxf(m, __shfl_xor(m, off));
  float s = m / 127.0f;
  if (s == 0.f) s = 1.f;
  auto qb = [&](float v) -> int {
    return ((int)fminf(fmaxf(rintf(v / s), -127.f), 127.f)) & 255;
  };
  const int p0 = qb(a.x) | (qb(a.y) << 8) | (qb(a.z) << 16) | (qb(a.w) << 24);
  const int p1 = qb(b.x) | (qb(b.y) << 8) | (qb(b.z) << 16) | (qb(b.w) << 24);
  const int p2 = qb(c.x) | (qb(c.y) << 8) | (qb(c.z) << 16) | (qb(c.w) << 24);
  int* q4 = (int*)qrow;
  q4[lane] = p0;
  q4[lane + 64] = p1;
  q4[lane + 128] = p2;
  if (lane == 0) *srow = s;
}

__device__ __forceinline__
void quant_all_job(int row, const float* hs, const float* w0, const float* w1,
                   const float* w2, const float* w3,
                   signed char* qx, float* sx,
                   signed char* q0, signed char* q1, signed char* q2,
                   signed char* q3,
                   float* s0, float* s1, float* s2, float* s3) {
  const float* src; signed char* qo; float* so; int r;
  if (row < R_TOT)             { src = hs; qo = qx; so = sx; r = row; }
  else if (row < R_TOT + 768)  { src = w0; qo = q0; so = s0; r = row - R_TOT; }
  else if (row < R_TOT + 1536) { src = w1; qo = q1; so = s1; r = row - R_TOT - 768; }
  else if (row < R_TOT + 2304) { src = w2; qo = q2; so = s2; r = row - R_TOT - 1536; }
  else                         { src = w3; qo = q3; so = s3; r = row - R_TOT - 2304; }
  quant_row_wave(src + (size_t)r * HID, qo + (size_t)r * HID, so + r);
}

__global__ __launch_bounds__(256)
void quant_rows(const float* __restrict__ src,
                signed char* __restrict__ qout, float* __restrict__ sout) {
  const int row = blockIdx.x * 4 + (threadIdx.x >> 6);
  quant_row_wave(src + (size_t)row * HID, qout + (size_t)row * HID, sout + row);
}

__global__ __launch_bounds__(256)
void quant_all(const float* hs, const float* w0, const float* w1,
               const float* w2, const float* w3,
               signed char* qx, float* sx,
               signed char* q0, signed char* q1, signed char* q2, signed char* q3,
               float* s0, float* s1, float* s2, float* s3) {
  const int row = blockIdx.x * 4 + (threadIdx.x >> 6);
  quant_all_job(row, hs, w0, w1, w2, w3, qx, sx, q0, q1, q2, q3, s0, s1, s2, s3);
}

// ---------------- int8 MFMA GEMM body: 128x64 tile, BK=128, double-buffered.
// Staging via global_load_lds width=16 with XOR swizzle (see earlier rounds).
// One barrier per k-iter; entry barrier protects LDS reuse when called in a
// job loop (mega-kernel). Bit-exact vs the 2-barrier version.
__device__ __forceinline__
void proj_stage(const signed char* __restrict__ qx,
                const signed char* __restrict__ qw,
                int row0, int col0, int k0,
                signed char* __restrict__ Ab, signed char* __restrict__ Bb,
                int w, int lr, int cg) {
  #pragma unroll
  for (int m = 0; m < 4; ++m) {
    const int ci = w * 4 + m;                       // A chunk 0..15
    gl_lds16(qx + (size_t)(row0 + ci * 8 + lr) * HID + k0 + cg * 16,
             Ab + ci * 1024);
  }
  #pragma unroll
  for (int m = 0; m < 2; ++m) {
    const int ci = w * 2 + m;                       // B chunk 0..7
    gl_lds16(qw + (size_t)(col0 + ci * 8 + lr) * HID + k0 + cg * 16,
             Bb + ci * 1024);
  }
}

__device__ __forceinline__
void proj_body(int mode, int bx, int by,
               const signed char* __restrict__ qx, const float* __restrict__ sx,
               const signed char* __restrict__ qw, const float* __restrict__ sw,
               const float* __restrict__ bias,
               signed char* __restrict__ qo, float* __restrict__ so,
               _Float16* __restrict__ vt, float* __restrict__ fo,
               signed char* Al, signed char* Bl) {
  const int tid = threadIdx.x;
  const int w = tid >> 6, lane = tid & 63;
  const int n = lane & 15, quad = lane >> 4;
  const int row0 = bx * 128, col0 = by * 64;
  const int lr = lane >> 3;          // row within 8-row chunk
  const int lc = lane & 7;           // col16 slot
  const int cg = lc ^ lr;            // swizzled global col16 to fetch
  v4i acc[2][4];
  #pragma unroll
  for (int s = 0; s < 2; ++s)
    #pragma unroll
    for (int j = 0; j < 4; ++j) acc[s][j] = (v4i){0, 0, 0, 0};

  __syncthreads();  // protect LDS reuse across job-loop iterations
  // prologue: stage k-tile 0 into buffer 0
  proj_stage(qx, qw, row0, col0, 0, Al, Bl, w, lr, cg);
  __syncthreads();

  #pragma unroll
  for (int it = 0; it < 6; ++it) {
    signed char* Ac = Al + (it & 1) * 16384;
    signed char* Bc = Bl + (it & 1) * 8192;
    if (it < 5)
      proj_stage(qx, qw, row0, col0, (it + 1) * 128,
                 Al + ((it & 1) ^ 1) * 16384, Bl + ((it & 1) ^ 1) * 8192,
                 w, lr, cg);
    #pragma unroll
    for (int ks4 = 0; ks4 < 8; ks4 += 4) {
      const int sw16 = ((quad + ks4) ^ (n & 7)) * 16;   // inverse swizzle
      const v4i af0 = *(const v4i*)&Ac[(w * 16 + n) * 128 + sw16];
      const v4i af1 = *(const v4i*)&Ac[(64 + w * 16 + n) * 128 + sw16];
      #pragma unroll
      for (int j = 0; j < 4; ++j) {
        const v4i bf = *(const v4i*)&Bc[(j * 16 + n) * 128 + sw16];
        acc[0][j] = __builtin_amdgcn_mfma_i32_16x16x64_i8(af0, bf, acc[0][j], 0, 0, 0);
        acc[1][j] = __builtin_amdgcn_mfma_i32_16x16x64_i8(af1, bf, acc[1][j], 0, 0, 0);
      }
    }
    if (it < 5) __syncthreads();
  }

  float swc4[4], bc4[4];
  #pragma unroll
  for (int j = 0; j < 4; ++j) {
    swc4[j] = sw[col0 + j * 16 + n];
    bc4[j] = bias[col0 + j * 16 + n];
  }
  #pragma unroll
  for (int s = 0; s < 2; ++s) {
    const int mrow = s * 64 + w * 16 + quad * 4;
    float sxr[4];
    #pragma unroll
    for (int r = 0; r < 4; ++r) sxr[r] = sx[row0 + mrow + r];
    float vals[4][4];  // [j][r]
    #pragma unroll
    for (int j = 0; j < 4; ++j)
      #pragma unroll
      for (int r = 0; r < 4; ++r)
        vals[j][r] = (float)acc[s][j][r] * (sxr[r] * swc4[j]) + bc4[j];
    if (mode == 1) {
      const int h = by;
      #pragma unroll
      for (int r = 0; r < 4; ++r) {
        float m = 0.f;
        #pragma unroll
        for (int j = 0; j < 4; ++j) m = fmaxf(m, fabsf(vals[j][r]));
        #pragma unroll
        for (int off = 1; off < 16; off <<= 1) m = fmaxf(m, __shfl_xor(m, off));
        float sq = m / 127.0f;
        if (sq == 0.f) sq = 1.f;
        const int grow = row0 + mrow + r;
        const int bidx = grow >> 9, sidx = grow & 511;
        const size_t rowidx = ((size_t)bidx * NHEAD + h) * SEQ + sidx;
        #pragma unroll
        for (int j = 0; j < 4; ++j) {
          float q = fminf(fmaxf(rintf(vals[j][r] / sq), -127.f), 127.f);
          qo[rowidx * HDIM + j * 16 + n] = (signed char)(int)q;
        }
        if (n == 0) so[rowidx] = sq;
      }
    } else if (mode == 2) {
      const int h = by;
      float srow[4];
      #pragma unroll
      for (int r = 0; r < 4; ++r) {
        float m = 0.f;
        #pragma unroll
        for (int j = 0; j < 4; ++j) m = fmaxf(m, fabsf(vals[j][r]));
        #pragma unroll
        for (int off = 1; off < 16; off <<= 1) m = fmaxf(m, __shfl_xor(m, off));
        float sq = m / 127.0f;
        if (sq == 0.f) sq = 1.f;
        srow[r] = sq;
      }
      const int grow0 = row0 + mrow;         // 4 consecutive k, same batch
      const int bidx = grow0 >> 9, sidx = grow0 & 511;
      const int kb = sidx >> 5, ko = sidx & 31;
      const size_t hbv = (size_t)bidx * NHEAD + h;
      #pragma unroll
      for (int j = 0; j < 4; ++j) {
        half4v hv;
        #pragma unroll
        for (int r = 0; r < 4; ++r) {
          float q = fminf(fmaxf(rintf(vals[j][r] / srow[r]), -127.f), 127.f);
          hv[r] = (_Float16)(q * srow[r]);
        }
        *(half4v*)(vt + ((hbv * 16 + kb) * 64 + j * 16 + n) * 32 + ko) = hv;
      }
    } else {
      #pragma unroll
      for (int r = 0; r < 4; ++r) {
        const size_t base = (size_t)(row0 + mrow + r) * HID + col0;
        #pragma unroll
        for (int j = 0; j < 4; ++j)
          fo[base + j * 16 + n] = vals[j][r];
      }
    }
  }
}

// fallback standalone wrappers ----------------------------------------------
__global__ __launch_bounds__(256)
void proj_qkv(const signed char* __restrict__ qx, const float* __restrict__ sx,
              const signed char* qwq, const float* swq, const float* bq,
              signed char* qqd, float* qqs,
              const signed char* qwk, const float* swk, const float* bk,
              signed char* qkd, float* qks,
              const signed char* qwv, const float* swv, const float* bv,
              _Float16* vt2) {
  __shared__ __align__(16) signed char Al[2 * 128 * 128];
  __shared__ __align__(16) signed char Bl[2 * 64 * 128];
  if (blockIdx.z == 0)
    proj_body(1, blockIdx.x, blockIdx.y, qx, sx, qwq, swq, bq, qqd, qqs, nullptr, nullptr, Al, Bl);
  else if (blockIdx.z == 1)
    proj_body(1, blockIdx.x, blockIdx.y, qx, sx, qwk, swk, bk, qkd, qks, nullptr, nullptr, Al, Bl);
  else
    proj_body(2, blockIdx.x, blockIdx.y, qx, sx, qwv, swv, bv, nullptr, nullptr, vt2, nullptr, Al, Bl);
}

__global__ __launch_bounds__(256)
void proj_out(const signed char* __restrict__ qx, const float* __restrict__ sx,
              const signed char* qw, const float* sw, const float* bias,
              float* fo) {
  __shared__ __align__(16) signed char Al[2 * 128 * 128];
  __shared__ __align__(16) signed char Bl[2 * 64 * 128];
  proj_body(0, blockIdx.x, blockIdx.y, qx, sx, qw, sw, bias, nullptr, nullptr, nullptr, fo, Al, Bl);
}

// ---------------- attention helpers ---------------------------------------
__device__ __forceinline__
void softmax_exp_tile(float (&s)[8][4], float mx26, const float4* __restrict__ pt4,
                      float& sum_out, float& amax_out) {
  float sum = 0.f, amax = 0.f;
  #pragma unroll
  for (int t = 0; t < 8; ++t) {
    #pragma unroll
    for (int r = 0; r < 4; ++r) {
      float sh = s[t][r] - mx26;              // == (s-mx)*2^26 exactly
      sh = fmaxf(sh, -671088640.0f);          // clamp at -10*2^26
      const float tq = rintf(sh);
      const float xc = tq * 1.4901161193847656e-08f;  // *2^-26 (exact)
      int g = (int)((xc + 10.0f) * 1.2f);     // >=0 since xc>=-10
      g = g > 11 ? 11 : g;
      float4 E = pt4[g];
      int gn = g + ((xc >= E.y) ? 1 : 0) - ((xc < E.x) ? 1 : 0);
      gn = gn < 0 ? 0 : (gn > 11 ? 11 : gn);
      if (gn != g) E = pt4[gn];               // rare boundary fixup
      const float e = __fadd_rn(__fmul_rn(E.z, xc), E.w);
      s[t][r] = e;
      sum += e;
      amax = fmaxf(amax, fabsf(e));
    }
  }
  sum += __shfl_xor(sum, 16);
  sum += __shfl_xor(sum, 32);
  amax = fmaxf(amax, __shfl_xor(amax, 16));
  amax = fmaxf(amax, __shfl_xor(amax, 32));
  sum_out = sum; amax_out = amax;
}

__device__ __forceinline__
void quant_pack_tile(const float (&s)[8][4], float t127,
                     _Float16* __restrict__ phtrow, int w, int quad) {
  #pragma unroll
  for (int t = 0; t < 8; ++t) {
    half4v hq;
    #pragma unroll
    for (int r = 0; r < 4; ++r) {
      const float qf = fminf(fmaxf(rintf(s[t][r] * t127), -127.f), 127.f);
      hq[r] = (_Float16)qf;
    }
    *(half4v*)&phtrow[(t * 4 + w) * 16 + quad * 4] = hq;
  }
}

__device__ __forceinline__
v4f pv_tile(const _Float16* __restrict__ vbase, const _Float16* __restrict__ prow) {
  v4f acc = {0.f, 0.f, 0.f, 0.f};
  #pragma unroll
  for (int kt = 0; kt < 16; ++kt) {
    const half8 bf = *(const half8*)(vbase + kt * 2048);
    acc = __builtin_amdgcn_mfma_f32_16x16x32_f16(*(const half8*)(prow + kt * 32), bf, acc, 0, 0, 0);
  }
  return acc;
}

// ---------------- fused attention body: dual-tile, overlapped phases -------
// P1(both) | 2a(t0) | 2b(t0)+2a(t1) | PV(t0)+2b(t1) | PV(t1)  — 4 barriers.
// Job-loop safe: first LDS write of next job (red_max, phase 1, pre-bar1)
// touches a region not read after bar3 of the previous job; PhT/psa writes of
// next job happen only after bar2, by which point all waves have passed their
// own phase E (bar1+bar2 ordering).
#define PSTR 520  // PhT row stride in halves (16B-aligned rows)
__device__ __forceinline__
void attn_body(int bxq, int hh, int bz,
               const signed char* __restrict__ qq, const float* __restrict__ qss,
               const signed char* __restrict__ qk, const float* __restrict__ kss,
               const _Float16* __restrict__ vt2, float* __restrict__ ctx,
               _Float16* __restrict__ PhT0, _Float16* __restrict__ PhT1,
               float* __restrict__ red_maxp, float* __restrict__ red_sump,
               float* __restrict__ red_amaxp, float* __restrict__ psap,
               const float4* __restrict__ pt4) {
  const int tid = threadIdx.x;
  const int q0 = bxq * 32;
  const size_t hb = (size_t)bz * NHEAD + hh;
  const signed char* qqh = qq + (hb * SEQ + q0) * HDIM;
  const signed char* qkh = qk + hb * SEQ * HDIM;
  const float* ksp = kss + hb * SEQ;

  const int w = tid >> 6, lane = tid & 63;
  const int n = lane & 15, quad = lane >> 4;

  // ---- Phase 1: S^T via i8 MFMA (A=K rows, B=Q rows), two q-tiles ----
  float s26[2][8][4];
  {
    const v4i qf0 = *(const v4i*)(qqh + (size_t)n * HDIM + quad * 16);
    const v4i qf1 = *(const v4i*)(qqh + (size_t)(16 + n) * HDIM + quad * 16);
    const float qs0 = (qss[hb * SEQ + q0 + n] * 0.125f) * 67108864.0f;
    const float qs1 = (qss[hb * SEQ + q0 + 16 + n] * 0.125f) * 67108864.0f;
    float vmax0 = -3.0e38f, vmax1 = -3.0e38f;
    #pragma unroll
    for (int t = 0; t < 8; ++t) {
      const int kc0 = (t * 4 + w) * 16;
      const v4i kfrag = *(const v4i*)(qkh + (size_t)(kc0 + n) * HDIM + quad * 16);
      const float4 ks4 = *(const float4*)(ksp + kc0 + quad * 4);
      v4i zero = {};
      const v4i a0 = __builtin_amdgcn_mfma_i32_16x16x64_i8(kfrag, qf0, zero, 0, 0, 0);
      const v4i a1 = __builtin_amdgcn_mfma_i32_16x16x64_i8(kfrag, qf1, zero, 0, 0, 0);
      const float ks[4] = {ks4.x, ks4.y, ks4.z, ks4.w};
      #pragma unroll
      for (int r = 0; r < 4; ++r) {
        const float v0 = (float)a0[r] * (qs0 * ks[r]);
        const float v1 = (float)a1[r] * (qs1 * ks[r]);
        s26[0][t][r] = v0; vmax0 = fmaxf(vmax0, v0);
        s26[1][t][r] = v1; vmax1 = fmaxf(vmax1, v1);
      }
    }
    vmax0 = fmaxf(vmax0, __shfl_xor(vmax0, 16));
    vmax0 = fmaxf(vmax0, __shfl_xor(vmax0, 32));
    vmax1 = fmaxf(vmax1, __shfl_xor(vmax1, 16));
    vmax1 = fmaxf(vmax1, __shfl_xor(vmax1, 32));
    if (quad == 0) { red_maxp[n * 4 + w] = vmax0; red_maxp[(16 + n) * 4 + w] = vmax1; }
  }
  __syncthreads();  // bar1

  // ---- Phase B: 2a(t0) ----
  {
    const float4 rm = *(const float4*)(red_maxp + n * 4);
    const float mx26 = fmaxf(fmaxf(rm.x, rm.y), fmaxf(rm.z, rm.w));
    float sum, amax;
    softmax_exp_tile(s26[0], mx26, pt4, sum, amax);
    if (quad == 0) { red_sump[n * 4 + w] = sum; red_amaxp[n * 4 + w] = amax; }
  }
  __syncthreads();  // bar2

  // ---- Phase C: 2b(t0) -> PhT0  +  2a(t1) ----
  {
    const float4 rs = *(const float4*)(red_sump + n * 4);
    const float4 ra = *(const float4*)(red_amaxp + n * 4);
    float denom = (rs.x + rs.y) + (rs.z + rs.w);
    denom = __fadd_rn(denom, 1e-9f);
    const float rden = 1.0f / denom;
    const float am = fmaxf(fmaxf(ra.x, ra.y), fmaxf(ra.z, ra.w));
    float ps = (am * rden) / 127.0f;
    if (ps == 0.f) ps = 1.f;
    if (w == 0 && quad == 0) psap[n] = ps;
    const float t127 = 127.0f / am;
    quant_pack_tile(s26[0], t127, &PhT0[n * PSTR], w, quad);

    const float4 rm = *(const float4*)(red_maxp + (16 + n) * 4);
    const float mx26 = fmaxf(fmaxf(rm.x, rm.y), fmaxf(rm.z, rm.w));
    float sum, amax;
    softmax_exp_tile(s26[1], mx26, pt4, sum, amax);
    if (quad == 0) { red_sump[(16 + n) * 4 + w] = sum; red_amaxp[(16 + n) * 4 + w] = amax; }
  }
  __syncthreads();  // bar3

  const _Float16* vbase = vt2 + ((size_t)hb * 16 * 64 + (w * 16 + n)) * 32 + quad * 8;

  // ---- Phase D: PV(t0)  +  2b(t1) -> PhT1 ----
  {
    const v4f acc0 = pv_tile(vbase, &PhT0[n * PSTR + quad * 8]);

    const float4 rs = *(const float4*)(red_sump + (16 + n) * 4);
    const float4 ra = *(const float4*)(red_amaxp + (16 + n) * 4);
    float denom = (rs.x + rs.y) + (rs.z + rs.w);
    denom = __fadd_rn(denom, 1e-9f);
    const float rden = 1.0f / denom;
    const float am = fmaxf(fmaxf(ra.x, ra.y), fmaxf(ra.z, ra.w));
    float ps = (am * rden) / 127.0f;
    if (ps == 0.f) ps = 1.f;
    if (w == 0 && quad == 0) psap[16 + n] = ps;
    const float t127 = 127.0f / am;
    quant_pack_tile(s26[1], t127, &PhT1[n * PSTR], w, quad);

    #pragma unroll
    for (int r = 0; r < 4; ++r) {
      const int row = quad * 4 + r;
      ctx[((size_t)bz * SEQ + q0 + row) * HID + (size_t)hh * HDIM + w * 16 + n] =
          acc0[r] * psap[row];
    }
  }
  __syncthreads();  // bar4

  // ---- Phase E: PV(t1) ----
  {
    const v4f acc1 = pv_tile(vbase, &PhT1[n * PSTR + quad * 8]);
    #pragma unroll
    for (int r = 0; r < 4; ++r) {
      const int row = quad * 4 + r;
      ctx[((size_t)bz * SEQ + q0 + 16 + row) * HID + (size_t)hh * HDIM + w * 16 + n] =
          acc1[r] * psap[16 + row];
    }
  }
}

__global__ __launch_bounds__(256)
void attn_kernel(const signed char* __restrict__ qq, const float* __restrict__ qss,
                 const signed char* __restrict__ qk, const float* __restrict__ kss,
                 const _Float16* __restrict__ vt2,
                 float* __restrict__ ctx, const PlaConsts pc) {
  __shared__ __align__(16) _Float16 PhT[2][16 * PSTR];
  __shared__ __align__(16) float red_max[2][16][4];
  __shared__ __align__(16) float red_sum[2][16][4];
  __shared__ __align__(16) float red_amax[2][16][4];
  __shared__ __align__(16) float psa[2][16];
  __shared__ __align__(16) float4 pt4[12];
  if (threadIdx.x < 12)
    pt4[threadIdx.x] = make_float4(pc.b[threadIdx.x], pc.b[threadIdx.x + 1],
                                   pc.m[threadIdx.x], pc.c[threadIdx.x]);
  attn_body(blockIdx.x, blockIdx.y, blockIdx.z, qq, qss, qk, kss, vt2, ctx,
            &PhT[0][0], &PhT[1][0], &red_max[0][0][0], &red_sum[0][0][0],
            &red_amax[0][0][0], &psa[0][0], pt4);
}

// ---------------- cooperative mega-kernel ----------------------------------
struct MegaArgs {
  const float *hs, *Wq, *bq, *Wk, *bk, *Wv, *bv, *Wo, *bo;
  float* out;
  signed char* qx; float* sx;
  signed char *qwq, *qwk, *qwv, *qwo;
  float *swq, *swk, *swv, *swo;
  signed char* qqd; float* qqs;
  signed char* qkd; float* qks;
  float* ctx; _Float16* vt2;
  PlaConsts pc;
};

__global__ __launch_bounds__(256, 3)
void mega_kernel(MegaArgs a) {
  __shared__ __align__(16) char smem[49152];
  signed char* Al = (signed char*)smem;            // 32 KB (2 x 16K)
  signed char* Bl = (signed char*)smem + 32768;    // 16 KB (2 x 8K)
  cg::grid_group grid = cg::this_grid();
  const int bid = blockIdx.x;
  const int wv = threadIdx.x >> 6;

  // stage 1: quantize hs + 4 weight matrices (7168 rows, 4 rows/block-job)
  for (int j = bid; j < 1792; j += GRID_N)
    quant_all_job(j * 4 + wv, a.hs, a.Wq, a.Wk, a.Wv, a.Wo, a.qx, a.sx,
                  a.qwq, a.qwk, a.qwv, a.qwo, a.swq, a.swk, a.swv, a.swo);
  grid.sync();

  // stage 2: QKV projections (1152 tile-jobs)
  for (int j = bid; j < 1152; j += GRID_N) {
    const int z = j / 384, rem = j - z * 384;
    const int by = rem >> 5, bx = rem & 31;
    if (z == 0)
      proj_body(1, bx, by, a.qx, a.sx, a.qwq, a.swq, a.bq, a.qqd, a.qqs,
                nullptr, nullptr, Al, Bl);
    else if (z == 1)
      proj_body(1, bx, by, a.qx, a.sx, a.qwk, a.swk, a.bk, a.qkd, a.qks,
                nullptr, nullptr, Al, Bl);
    else
      proj_body(2, bx, by, a.qx, a.sx, a.qwv, a.swv, a.bv, nullptr, nullptr,
                a.vt2, nullptr, Al, Bl);
  }
  grid.sync();

  // stage 3: attention (1536 jobs, exactly 2 per block)
  {
    _Float16* PhT0 = (_Float16*)smem;
    _Float16* PhT1 = PhT0 + 16 * PSTR;               // ends at 33280 B
    float* red_maxp  = (float*)(smem + 33280);       // 512 B
    float* red_sump  = (float*)(smem + 33792);       // 512 B
    float* red_amaxp = (float*)(smem + 34304);       // 512 B
    float* psap      = (float*)(smem + 34816);       // 128 B
    float4* pt4      = (float4*)(smem + 34944);      // 192 B
    if (threadIdx.x < 12)
      pt4[threadIdx.x] = make_float4(a.pc.b[threadIdx.x], a.pc.b[threadIdx.x + 1],
                                     a.pc.m[threadIdx.x], a.pc.c[threadIdx.x]);
    for (int j = bid; j < 1536; j += GRID_N) {
      const int bx = j & 15, t = j >> 4, by = t % 12, bz = t / 12;
      attn_body(bx, by, bz, a.qqd, a.qqs, a.qkd, a.qks, a.vt2, a.ctx,
                PhT0, PhT1, red_maxp, red_sump, red_amaxp, psap, pt4);
    }
  }
  grid.sync();

  // stage 4: quantize ctx rows into qx/sx alias (4096 rows)
  for (int j = bid; j < 1024; j += GRID_N) {
    const int row = j * 4 + wv;
    quant_row_wave(a.ctx + (size_t)row * HID, a.qx + (size_t)row * HID,
                   a.sx + row);
  }
  grid.sync();

  // stage 5: output projection (384 jobs)
  for (int j = bid; j < 384; j += GRID_N) {
    const int by = j >> 5, bx = j & 31;
    proj_body(0, bx, by, a.qx, a.sx, a.qwo, a.swo, a.bo, nullptr, nullptr,
              nullptr, a.out, Al, Bl);
  }
}

// --------------------------------------------------------------------------
extern "C" void kernel_launch(void* const* d_in, const int* in_sizes, int n_in,
                              void* d_out, int out_size, void* d_ws, size_t ws_size,
                              hipStream_t stream) {
  (void)in_sizes; (void)n_in; (void)out_size; (void)ws_size;
  const float* hs = (const float*)d_in[0];
  const float* Wq = (const float*)d_in[1];
  const float* bq = (const float*)d_in[2];
  const float* Wk = (const float*)d_in[3];
  const float* bk = (const float*)d_in[4];
  const float* Wv = (const float*)d_in[5];
  const float* bv = (const float*)d_in[6];
  const float* Wo = (const float*)d_in[7];
  const float* bo = (const float*)d_in[8];
  float* out = (float*)d_out;

  char* ws = (char*)d_ws;
  size_t off = 0;
  auto alloc = [&](size_t bytes) -> char* {
    char* p = ws + off;
    off += (bytes + 255) & ~(size_t)255;
    return p;
  };
  signed char* qx  = (signed char*)alloc((size_t)R_TOT * HID);
  float*       sx  = (float*)alloc((size_t)R_TOT * 4);
  signed char* qwq = (signed char*)alloc((size_t)HID * HID);
  signed char* qwk = (signed char*)alloc((size_t)HID * HID);
  signed char* qwv = (signed char*)alloc((size_t)HID * HID);
  signed char* qwo = (signed char*)alloc((size_t)HID * HID);
  float*       swq = (float*)alloc((size_t)HID * 4);
  float*       swk = (float*)alloc((size_t)HID * 4);
  float*       swv = (float*)alloc((size_t)HID * 4);
  float*       swo = (float*)alloc((size_t)HID * 4);
  signed char* qqd = (signed char*)alloc((size_t)R_TOT * HID);
  float*       qqs = (float*)alloc((size_t)BATCH * NHEAD * SEQ * 4);
  signed char* qkd = (signed char*)alloc((size_t)R_TOT * HID);
  float*       qks = (float*)alloc((size_t)BATCH * NHEAD * SEQ * 4);
  float*       ctx = (float*)alloc((size_t)R_TOT * HID * 4);
  _Float16*    vt2 = (_Float16*)alloc((size_t)BATCH * NHEAD * HDIM * SEQ * 2);
  // alias: qx/sx are dead after the QKV projections
  signed char* qc  = qx;
  float*       scs = sx;

  MegaArgs ma;
  ma.hs = hs; ma.Wq = Wq; ma.bq = bq; ma.Wk = Wk; ma.bk = bk;
  ma.Wv = Wv; ma.bv = bv; ma.Wo = Wo; ma.bo = bo; ma.out = out;
  ma.qx = qx; ma.sx = sx;
  ma.qwq = qwq; ma.qwk = qwk; ma.qwv = qwv; ma.qwo = qwo;
  ma.swq = swq; ma.swk = swk; ma.swv = swv; ma.swo = swo;
  ma.qqd = qqd; ma.qqs = qqs; ma.qkd = qkd; ma.qks = qks;
  ma.ctx = ctx; ma.vt2 = vt2;
  ma.pc = g_pla;

  void* kargs[] = { (void*)&ma };
  hipError_t err = hipLaunchCooperativeKernel(
      reinterpret_cast<const void*>(&mega_kernel),
      dim3(GRID_N), dim3(256), kargs, 0, stream);
  if (err != hipSuccess) {
    (void)hipGetLastError();  // clear sticky error, fall back to 5 kernels
    quant_all<<<(R_TOT + 4 * HID) / 4, 256, 0, stream>>>(
        hs, Wq, Wk, Wv, Wo, qx, sx,
        qwq, qwk, qwv, qwo, swq, swk, swv, swo);
    proj_qkv<<<dim3(R_TOT / 128, HID / 64, 3), 256, 0, stream>>>(
        qx, sx, qwq, swq, bq, qqd, qqs,
        qwk, swk, bk, qkd, qks,
        qwv, swv, bv, vt2);
    attn_kernel<<<dim3(SEQ / 32, NHEAD, BATCH), 256, 0, stream>>>(
        qqd, qqs, qkd, qks, vt2, ctx, g_pla);
    quant_rows<<<R_TOT / 4, 256, 0, stream>>>(ctx, qc, scs);
    proj_out<<<dim3(R_TOT / 128, HID / 64), 256, 0, stream>>>(
        qc, scs, qwo, swo, bo, out);
  }
}

// Round 4
// 394.972 us; speedup vs baseline: 1.3939x; 1.3939x over previous
//
#include <hip/hip_runtime.h>
#include <hip/hip_cooperative_groups.h>
#include <cmath>

namespace cg = cooperative_groups;

#define R_TOT 4096   // B*S rows
#define HID   768
#define NHEAD 12
#define HDIM  64
#define SEQ   512
#define BATCH 8
#define GRID_N 512   // 2 blocks/CU x 256 CU — co-resident for grid.sync
                     // (r3 post-mortem: 3/CU forced VGPR<=128 -> s26 spills)

typedef int   v4i  __attribute__((ext_vector_type(4)));
typedef float v4f  __attribute__((ext_vector_type(4)));
typedef _Float16 half8 __attribute__((ext_vector_type(8)));
typedef _Float16 half4v __attribute__((ext_vector_type(4)));

// Direct global->LDS DMA, 16B per lane. HW semantics (m104/m108): dest =
// readfirstlane(ldsptr) + lane*16 — pass the wave-uniform chunk base.
__device__ __forceinline__ void gl_lds16(const signed char* g, signed char* l) {
  __builtin_amdgcn_global_load_lds(
      (const __attribute__((address_space(1))) void*)g,
      (__attribute__((address_space(3))) void*)l, 16, 0, 0);
}

// ---------------- PLA coefficients (host, replicates np.polyfit in f64) ----
struct PlaConsts { float m[12]; float c[12]; float b[13]; };

static PlaConsts build_pla() {
  PlaConsts pc;
  const int NPTS = 1001;
  static double xs[NPTS], ys[NPTS];
  const double step = 10.0 / 1000.0;
  for (int j = 0; j < NPTS; ++j) xs[j] = (double)j * step + (-10.0);
  xs[NPTS - 1] = 0.0;
  for (int j = 0; j < NPTS; ++j) ys[j] = std::exp(xs[j]);
  double bnd[13];
  const double step2 = 10.0 / 12.0;
  for (int k = 0; k < 13; ++k) bnd[k] = (double)k * step2 + (-10.0);
  bnd[12] = 0.0;
  for (int i = 0; i < 12; ++i) {
    const double a = bnd[i], bb = bnd[i + 1];
    double sx = 0, sy = 0; int n = 0;
    for (int j = 0; j < NPTS; ++j)
      if (xs[j] >= a && xs[j] <= bb) { sx += xs[j]; sy += ys[j]; ++n; }
    const double xm = sx / n, ym = sy / n;
    double sxx = 0, sxy = 0;
    for (int j = 0; j < NPTS; ++j)
      if (xs[j] >= a && xs[j] <= bb) {
        const double dx = xs[j] - xm;
        sxx += dx * dx; sxy += dx * (ys[j] - ym);
      }
    const double m = sxy / sxx;
    pc.m[i] = (float)m;
    pc.c[i] = (float)(ym - m * xm);
  }
  for (int k = 0; k < 13; ++k) pc.b[k] = (float)bnd[k];
  return pc;
}
static const PlaConsts g_pla = build_pla();

// ---------------- per-row abs-max int8 quantization (768 cols) -------------
__device__ __forceinline__ void quant_row_wave(const float* __restrict__ x,
                                               signed char* __restrict__ qrow,
                                               float* __restrict__ srow) {
  const int lane = threadIdx.x & 63;
  const float4* x4 = (const float4*)x;
  const float4 a = x4[lane];
  const float4 b = x4[lane + 64];
  const float4 c = x4[lane + 128];
  float m = fmaxf(fmaxf(fabsf(a.x), fabsf(a.y)), fmaxf(fabsf(a.z), fabsf(a.w)));
  m = fmaxf(m, fmaxf(fmaxf(fabsf(b.x), fabsf(b.y)), fmaxf(fabsf(b.z), fabsf(b.w))));
  m = fmaxf(m, fmaxf(fmaxf(fabsf(c.x), fabsf(c.y)), fmaxf(fabsf(c.z), fabsf(c.w))));
  #pragma unroll
  for (int off = 32; off; off >>= 1) m = fmaxf(m, __shfl_xor(m, off));
  float s = m / 127.0f;
  if (s == 0.f) s = 1.f;
  auto qb = [&](float v) -> int {
    return ((int)fminf(fmaxf(rintf(v / s), -127.f), 127.f)) & 255;
  };
  const int p0 = qb(a.x) | (qb(a.y) << 8) | (qb(a.z) << 16) | (qb(a.w) << 24);
  const int p1 = qb(b.x) | (qb(b.y) << 8) | (qb(b.z) << 16) | (qb(b.w) << 24);
  const int p2 = qb(c.x) | (qb(c.y) << 8) | (qb(c.z) << 16) | (qb(c.w) << 24);
  int* q4 = (int*)qrow;
  q4[lane] = p0;
  q4[lane + 64] = p1;
  q4[lane + 128] = p2;
  if (lane == 0) *srow = s;
}

__device__ __forceinline__
void quant_all_job(int row, const float* hs, const float* w0, const float* w1,
                   const float* w2, const float* w3,
                   signed char* qx, float* sx,
                   signed char* q0, signed char* q1, signed char* q2,
                   signed char* q3,
                   float* s0, float* s1, float* s2, float* s3) {
  const float* src; signed char* qo; float* so; int r;
  if (row < R_TOT)             { src = hs; qo = qx; so = sx; r = row; }
  else if (row < R_TOT + 768)  { src = w0; qo = q0; so = s0; r = row - R_TOT; }
  else if (row < R_TOT + 1536) { src = w1; qo = q1; so = s1; r = row - R_TOT - 768; }
  else if (row < R_TOT + 2304) { src = w2; qo = q2; so = s2; r = row - R_TOT - 1536; }
  else                         { src = w3; qo = q3; so = s3; r = row - R_TOT - 2304; }
  quant_row_wave(src + (size_t)r * HID, qo + (size_t)r * HID, so + r);
}

__global__ __launch_bounds__(256)
void quant_rows(const float* __restrict__ src,
                signed char* __restrict__ qout, float* __restrict__ sout) {
  const int row = blockIdx.x * 4 + (threadIdx.x >> 6);
  quant_row_wave(src + (size_t)row * HID, qout + (size_t)row * HID, sout + row);
}

__global__ __launch_bounds__(256)
void quant_all(const float* hs, const float* w0, const float* w1,
               const float* w2, const float* w3,
               signed char* qx, float* sx,
               signed char* q0, signed char* q1, signed char* q2, signed char* q3,
               float* s0, float* s1, float* s2, float* s3) {
  const int row = blockIdx.x * 4 + (threadIdx.x >> 6);
  quant_all_job(row, hs, w0, w1, w2, w3, qx, sx, q0, q1, q2, q3, s0, s1, s2, s3);
}

// ---------------- int8 MFMA GEMM body: 128x64 tile, BK=128, double-buffered.
// Staging via global_load_lds width=16 with XOR swizzle (see earlier rounds).
// One barrier per k-iter; entry barrier protects LDS reuse when called in a
// job loop (mega-kernel). Bit-exact vs the 2-barrier version.
__device__ __forceinline__
void proj_stage(const signed char* __restrict__ qx,
                const signed char* __restrict__ qw,
                int row0, int col0, int k0,
                signed char* __restrict__ Ab, signed char* __restrict__ Bb,
                int w, int lr, int cg) {
  #pragma unroll
  for (int m = 0; m < 4; ++m) {
    const int ci = w * 4 + m;                       // A chunk 0..15
    gl_lds16(qx + (size_t)(row0 + ci * 8 + lr) * HID + k0 + cg * 16,
             Ab + ci * 1024);
  }
  #pragma unroll
  for (int m = 0; m < 2; ++m) {
    const int ci = w * 2 + m;                       // B chunk 0..7
    gl_lds16(qw + (size_t)(col0 + ci * 8 + lr) * HID + k0 + cg * 16,
             Bb + ci * 1024);
  }
}

__device__ __forceinline__
void proj_body(int mode, int bx, int by,
               const signed char* __restrict__ qx, const float* __restrict__ sx,
               const signed char* __restrict__ qw, const float* __restrict__ sw,
               const float* __restrict__ bias,
               signed char* __restrict__ qo, float* __restrict__ so,
               _Float16* __restrict__ vt, float* __restrict__ fo,
               signed char* Al, signed char* Bl) {
  const int tid = threadIdx.x;
  const int w = tid >> 6, lane = tid & 63;
  const int n = lane & 15, quad = lane >> 4;
  const int row0 = bx * 128, col0 = by * 64;
  const int lr = lane >> 3;          // row within 8-row chunk
  const int lc = lane & 7;           // col16 slot
  const int cg = lc ^ lr;            // swizzled global col16 to fetch
  v4i acc[2][4];
  #pragma unroll
  for (int s = 0; s < 2; ++s)
    #pragma unroll
    for (int j = 0; j < 4; ++j) acc[s][j] = (v4i){0, 0, 0, 0};

  __syncthreads();  // protect LDS reuse across job-loop iterations
  // prologue: stage k-tile 0 into buffer 0
  proj_stage(qx, qw, row0, col0, 0, Al, Bl, w, lr, cg);
  __syncthreads();

  #pragma unroll
  for (int it = 0; it < 6; ++it) {
    signed char* Ac = Al + (it & 1) * 16384;
    signed char* Bc = Bl + (it & 1) * 8192;
    if (it < 5)
      proj_stage(qx, qw, row0, col0, (it + 1) * 128,
                 Al + ((it & 1) ^ 1) * 16384, Bl + ((it & 1) ^ 1) * 8192,
                 w, lr, cg);
    #pragma unroll
    for (int ks4 = 0; ks4 < 8; ks4 += 4) {
      const int sw16 = ((quad + ks4) ^ (n & 7)) * 16;   // inverse swizzle
      const v4i af0 = *(const v4i*)&Ac[(w * 16 + n) * 128 + sw16];
      const v4i af1 = *(const v4i*)&Ac[(64 + w * 16 + n) * 128 + sw16];
      #pragma unroll
      for (int j = 0; j < 4; ++j) {
        const v4i bf = *(const v4i*)&Bc[(j * 16 + n) * 128 + sw16];
        acc[0][j] = __builtin_amdgcn_mfma_i32_16x16x64_i8(af0, bf, acc[0][j], 0, 0, 0);
        acc[1][j] = __builtin_amdgcn_mfma_i32_16x16x64_i8(af1, bf, acc[1][j], 0, 0, 0);
      }
    }
    if (it < 5) __syncthreads();
  }

  float swc4[4], bc4[4];
  #pragma unroll
  for (int j = 0; j < 4; ++j) {
    swc4[j] = sw[col0 + j * 16 + n];
    bc4[j] = bias[col0 + j * 16 + n];
  }
  #pragma unroll
  for (int s = 0; s < 2; ++s) {
    const int mrow = s * 64 + w * 16 + quad * 4;
    float sxr[4];
    #pragma unroll
    for (int r = 0; r < 4; ++r) sxr[r] = sx[row0 + mrow + r];
    float vals[4][4];  // [j][r]
    #pragma unroll
    for (int j = 0; j < 4; ++j)
      #pragma unroll
      for (int r = 0; r < 4; ++r)
        vals[j][r] = (float)acc[s][j][r] * (sxr[r] * swc4[j]) + bc4[j];
    if (mode == 1) {
      const int h = by;
      #pragma unroll
      for (int r = 0; r < 4; ++r) {
        float m = 0.f;
        #pragma unroll
        for (int j = 0; j < 4; ++j) m = fmaxf(m, fabsf(vals[j][r]));
        #pragma unroll
        for (int off = 1; off < 16; off <<= 1) m = fmaxf(m, __shfl_xor(m, off));
        float sq = m / 127.0f;
        if (sq == 0.f) sq = 1.f;
        const int grow = row0 + mrow + r;
        const int bidx = grow >> 9, sidx = grow & 511;
        const size_t rowidx = ((size_t)bidx * NHEAD + h) * SEQ + sidx;
        #pragma unroll
        for (int j = 0; j < 4; ++j) {
          float q = fminf(fmaxf(rintf(vals[j][r] / sq), -127.f), 127.f);
          qo[rowidx * HDIM + j * 16 + n] = (signed char)(int)q;
        }
        if (n == 0) so[rowidx] = sq;
      }
    } else if (mode == 2) {
      const int h = by;
      float srow[4];
      #pragma unroll
      for (int r = 0; r < 4; ++r) {
        float m = 0.f;
        #pragma unroll
        for (int j = 0; j < 4; ++j) m = fmaxf(m, fabsf(vals[j][r]));
        #pragma unroll
        for (int off = 1; off < 16; off <<= 1) m = fmaxf(m, __shfl_xor(m, off));
        float sq = m / 127.0f;
        if (sq == 0.f) sq = 1.f;
        srow[r] = sq;
      }
      const int grow0 = row0 + mrow;         // 4 consecutive k, same batch
      const int bidx = grow0 >> 9, sidx = grow0 & 511;
      const int kb = sidx >> 5, ko = sidx & 31;
      const size_t hbv = (size_t)bidx * NHEAD + h;
      #pragma unroll
      for (int j = 0; j < 4; ++j) {
        half4v hv;
        #pragma unroll
        for (int r = 0; r < 4; ++r) {
          float q = fminf(fmaxf(rintf(vals[j][r] / srow[r]), -127.f), 127.f);
          hv[r] = (_Float16)(q * srow[r]);
        }
        *(half4v*)(vt + ((hbv * 16 + kb) * 64 + j * 16 + n) * 32 + ko) = hv;
      }
    } else {
      #pragma unroll
      for (int r = 0; r < 4; ++r) {
        const size_t base = (size_t)(row0 + mrow + r) * HID + col0;
        #pragma unroll
        for (int j = 0; j < 4; ++j)
          fo[base + j * 16 + n] = vals[j][r];
      }
    }
  }
}

// fallback standalone wrappers ----------------------------------------------
__global__ __launch_bounds__(256)
void proj_qkv(const signed char* __restrict__ qx, const float* __restrict__ sx,
              const signed char* qwq, const float* swq, const float* bq,
              signed char* qqd, float* qqs,
              const signed char* qwk, const float* swk, const float* bk,
              signed char* qkd, float* qks,
              const signed char* qwv, const float* swv, const float* bv,
              _Float16* vt2) {
  __shared__ __align__(16) signed char Al[2 * 128 * 128];
  __shared__ __align__(16) signed char Bl[2 * 64 * 128];
  if (blockIdx.z == 0)
    proj_body(1, blockIdx.x, blockIdx.y, qx, sx, qwq, swq, bq, qqd, qqs, nullptr, nullptr, Al, Bl);
  else if (blockIdx.z == 1)
    proj_body(1, blockIdx.x, blockIdx.y, qx, sx, qwk, swk, bk, qkd, qks, nullptr, nullptr, Al, Bl);
  else
    proj_body(2, blockIdx.x, blockIdx.y, qx, sx, qwv, swv, bv, nullptr, nullptr, vt2, nullptr, Al, Bl);
}

__global__ __launch_bounds__(256)
void proj_out(const signed char* __restrict__ qx, const float* __restrict__ sx,
              const signed char* qw, const float* sw, const float* bias,
              float* fo) {
  __shared__ __align__(16) signed char Al[2 * 128 * 128];
  __shared__ __align__(16) signed char Bl[2 * 64 * 128];
  proj_body(0, blockIdx.x, blockIdx.y, qx, sx, qw, sw, bias, nullptr, nullptr, nullptr, fo, Al, Bl);
}

// ---------------- attention helpers ---------------------------------------
__device__ __forceinline__
void softmax_exp_tile(float (&s)[8][4], float mx26, const float4* __restrict__ pt4,
                      float& sum_out, float& amax_out) {
  float sum = 0.f, amax = 0.f;
  #pragma unroll
  for (int t = 0; t < 8; ++t) {
    #pragma unroll
    for (int r = 0; r < 4; ++r) {
      float sh = s[t][r] - mx26;              // == (s-mx)*2^26 exactly
      sh = fmaxf(sh, -671088640.0f);          // clamp at -10*2^26
      const float tq = rintf(sh);
      const float xc = tq * 1.4901161193847656e-08f;  // *2^-26 (exact)
      int g = (int)((xc + 10.0f) * 1.2f);     // >=0 since xc>=-10
      g = g > 11 ? 11 : g;
      float4 E = pt4[g];
      int gn = g + ((xc >= E.y) ? 1 : 0) - ((xc < E.x) ? 1 : 0);
      gn = gn < 0 ? 0 : (gn > 11 ? 11 : gn);
      if (gn != g) E = pt4[gn];               // rare boundary fixup
      const float e = __fadd_rn(__fmul_rn(E.z, xc), E.w);
      s[t][r] = e;
      sum += e;
      amax = fmaxf(amax, fabsf(e));
    }
  }
  sum += __shfl_xor(sum, 16);
  sum += __shfl_xor(sum, 32);
  amax = fmaxf(amax, __shfl_xor(amax, 16));
  amax = fmaxf(amax, __shfl_xor(amax, 32));
  sum_out = sum; amax_out = amax;
}

__device__ __forceinline__
void quant_pack_tile(const float (&s)[8][4], float t127,
                     _Float16* __restrict__ phtrow, int w, int quad) {
  #pragma unroll
  for (int t = 0; t < 8; ++t) {
    half4v hq;
    #pragma unroll
    for (int r = 0; r < 4; ++r) {
      const float qf = fminf(fmaxf(rintf(s[t][r] * t127), -127.f), 127.f);
      hq[r] = (_Float16)qf;
    }
    *(half4v*)&phtrow[(t * 4 + w) * 16 + quad * 4] = hq;
  }
}

__device__ __forceinline__
v4f pv_tile(const _Float16* __restrict__ vbase, const _Float16* __restrict__ prow) {
  v4f acc = {0.f, 0.f, 0.f, 0.f};
  #pragma unroll
  for (int kt = 0; kt < 16; ++kt) {
    const half8 bf = *(const half8*)(vbase + kt * 2048);
    acc = __builtin_amdgcn_mfma_f32_16x16x32_f16(*(const half8*)(prow + kt * 32), bf, acc, 0, 0, 0);
  }
  return acc;
}

// ---------------- fused attention body: dual-tile, overlapped phases -------
// P1(both) | 2a(t0) | 2b(t0)+2a(t1) | PV(t0)+2b(t1) | PV(t1)  — 4 barriers.
// Job-loop safe: first LDS write of next job (red_max, phase 1, pre-bar1)
// touches a region not read after bar3 of the previous job; PhT/psa writes of
// next job happen only after bar2, by which point all waves have passed their
// own phase E (bar1+bar2 ordering).
#define PSTR 520  // PhT row stride in halves (16B-aligned rows)
__device__ __forceinline__
void attn_body(int bxq, int hh, int bz,
               const signed char* __restrict__ qq, const float* __restrict__ qss,
               const signed char* __restrict__ qk, const float* __restrict__ kss,
               const _Float16* __restrict__ vt2, float* __restrict__ ctx,
               _Float16* __restrict__ PhT0, _Float16* __restrict__ PhT1,
               float* __restrict__ red_maxp, float* __restrict__ red_sump,
               float* __restrict__ red_amaxp, float* __restrict__ psap,
               const float4* __restrict__ pt4) {
  const int tid = threadIdx.x;
  const int q0 = bxq * 32;
  const size_t hb = (size_t)bz * NHEAD + hh;
  const signed char* qqh = qq + (hb * SEQ + q0) * HDIM;
  const signed char* qkh = qk + hb * SEQ * HDIM;
  const float* ksp = kss + hb * SEQ;

  const int w = tid >> 6, lane = tid & 63;
  const int n = lane & 15, quad = lane >> 4;

  // ---- Phase 1: S^T via i8 MFMA (A=K rows, B=Q rows), two q-tiles ----
  float s26[2][8][4];
  {
    const v4i qf0 = *(const v4i*)(qqh + (size_t)n * HDIM + quad * 16);
    const v4i qf1 = *(const v4i*)(qqh + (size_t)(16 + n) * HDIM + quad * 16);
    const float qs0 = (qss[hb * SEQ + q0 + n] * 0.125f) * 67108864.0f;
    const float qs1 = (qss[hb * SEQ + q0 + 16 + n] * 0.125f) * 67108864.0f;
    float vmax0 = -3.0e38f, vmax1 = -3.0e38f;
    #pragma unroll
    for (int t = 0; t < 8; ++t) {
      const int kc0 = (t * 4 + w) * 16;
      const v4i kfrag = *(const v4i*)(qkh + (size_t)(kc0 + n) * HDIM + quad * 16);
      const float4 ks4 = *(const float4*)(ksp + kc0 + quad * 4);
      v4i zero = {};
      const v4i a0 = __builtin_amdgcn_mfma_i32_16x16x64_i8(kfrag, qf0, zero, 0, 0, 0);
      const v4i a1 = __builtin_amdgcn_mfma_i32_16x16x64_i8(kfrag, qf1, zero, 0, 0, 0);
      const float ks[4] = {ks4.x, ks4.y, ks4.z, ks4.w};
      #pragma unroll
      for (int r = 0; r < 4; ++r) {
        const float v0 = (float)a0[r] * (qs0 * ks[r]);
        const float v1 = (float)a1[r] * (qs1 * ks[r]);
        s26[0][t][r] = v0; vmax0 = fmaxf(vmax0, v0);
        s26[1][t][r] = v1; vmax1 = fmaxf(vmax1, v1);
      }
    }
    vmax0 = fmaxf(vmax0, __shfl_xor(vmax0, 16));
    vmax0 = fmaxf(vmax0, __shfl_xor(vmax0, 32));
    vmax1 = fmaxf(vmax1, __shfl_xor(vmax1, 16));
    vmax1 = fmaxf(vmax1, __shfl_xor(vmax1, 32));
    if (quad == 0) { red_maxp[n * 4 + w] = vmax0; red_maxp[(16 + n) * 4 + w] = vmax1; }
  }
  __syncthreads();  // bar1

  // ---- Phase B: 2a(t0) ----
  {
    const float4 rm = *(const float4*)(red_maxp + n * 4);
    const float mx26 = fmaxf(fmaxf(rm.x, rm.y), fmaxf(rm.z, rm.w));
    float sum, amax;
    softmax_exp_tile(s26[0], mx26, pt4, sum, amax);
    if (quad == 0) { red_sump[n * 4 + w] = sum; red_amaxp[n * 4 + w] = amax; }
  }
  __syncthreads();  // bar2

  // ---- Phase C: 2b(t0) -> PhT0  +  2a(t1) ----
  {
    const float4 rs = *(const float4*)(red_sump + n * 4);
    const float4 ra = *(const float4*)(red_amaxp + n * 4);
    float denom = (rs.x + rs.y) + (rs.z + rs.w);
    denom = __fadd_rn(denom, 1e-9f);
    const float rden = 1.0f / denom;
    const float am = fmaxf(fmaxf(ra.x, ra.y), fmaxf(ra.z, ra.w));
    float ps = (am * rden) / 127.0f;
    if (ps == 0.f) ps = 1.f;
    if (w == 0 && quad == 0) psap[n] = ps;
    const float t127 = 127.0f / am;
    quant_pack_tile(s26[0], t127, &PhT0[n * PSTR], w, quad);

    const float4 rm = *(const float4*)(red_maxp + (16 + n) * 4);
    const float mx26 = fmaxf(fmaxf(rm.x, rm.y), fmaxf(rm.z, rm.w));
    float sum, amax;
    softmax_exp_tile(s26[1], mx26, pt4, sum, amax);
    if (quad == 0) { red_sump[(16 + n) * 4 + w] = sum; red_amaxp[(16 + n) * 4 + w] = amax; }
  }
  __syncthreads();  // bar3

  const _Float16* vbase = vt2 + ((size_t)hb * 16 * 64 + (w * 16 + n)) * 32 + quad * 8;

  // ---- Phase D: PV(t0)  +  2b(t1) -> PhT1 ----
  {
    const v4f acc0 = pv_tile(vbase, &PhT0[n * PSTR + quad * 8]);

    const float4 rs = *(const float4*)(red_sump + (16 + n) * 4);
    const float4 ra = *(const float4*)(red_amaxp + (16 + n) * 4);
    float denom = (rs.x + rs.y) + (rs.z + rs.w);
    denom = __fadd_rn(denom, 1e-9f);
    const float rden = 1.0f / denom;
    const float am = fmaxf(fmaxf(ra.x, ra.y), fmaxf(ra.z, ra.w));
    float ps = (am * rden) / 127.0f;
    if (ps == 0.f) ps = 1.f;
    if (w == 0 && quad == 0) psap[16 + n] = ps;
    const float t127 = 127.0f / am;
    quant_pack_tile(s26[1], t127, &PhT1[n * PSTR], w, quad);

    #pragma unroll
    for (int r = 0; r < 4; ++r) {
      const int row = quad * 4 + r;
      ctx[((size_t)bz * SEQ + q0 + row) * HID + (size_t)hh * HDIM + w * 16 + n] =
          acc0[r] * psap[row];
    }
  }
  __syncthreads();  // bar4

  // ---- Phase E: PV(t1) ----
  {
    const v4f acc1 = pv_tile(vbase, &PhT1[n * PSTR + quad * 8]);
    #pragma unroll
    for (int r = 0; r < 4; ++r) {
      const int row = quad * 4 + r;
      ctx[((size_t)bz * SEQ + q0 + 16 + row) * HID + (size_t)hh * HDIM + w * 16 + n] =
          acc1[r] * psap[16 + row];
    }
  }
}

__global__ __launch_bounds__(256)
void attn_kernel(const signed char* __restrict__ qq, const float* __restrict__ qss,
                 const signed char* __restrict__ qk, const float* __restrict__ kss,
                 const _Float16* __restrict__ vt2,
                 float* __restrict__ ctx, const PlaConsts pc) {
  __shared__ __align__(16) _Float16 PhT[2][16 * PSTR];
  __shared__ __align__(16) float red_max[2][16][4];
  __shared__ __align__(16) float red_sum[2][16][4];
  __shared__ __align__(16) float red_amax[2][16][4];
  __shared__ __align__(16) float psa[2][16];
  __shared__ __align__(16) float4 pt4[12];
  if (threadIdx.x < 12)
    pt4[threadIdx.x] = make_float4(pc.b[threadIdx.x], pc.b[threadIdx.x + 1],
                                   pc.m[threadIdx.x], pc.c[threadIdx.x]);
  attn_body(blockIdx.x, blockIdx.y, blockIdx.z, qq, qss, qk, kss, vt2, ctx,
            &PhT[0][0], &PhT[1][0], &red_max[0][0][0], &red_sum[0][0][0],
            &red_amax[0][0][0], &psa[0][0], pt4);
}

// ---------------- cooperative mega-kernel ----------------------------------
struct MegaArgs {
  const float *hs, *Wq, *bq, *Wk, *bk, *Wv, *bv, *Wo, *bo;
  float* out;
  signed char* qx; float* sx;
  signed char *qwq, *qwk, *qwv, *qwo;
  float *swq, *swk, *swv, *swo;
  signed char* qqd; float* qqs;
  signed char* qkd; float* qks;
  float* ctx; _Float16* vt2;
  PlaConsts pc;
};

__global__ __launch_bounds__(256)
void mega_kernel(MegaArgs a) {
  __shared__ __align__(16) char smem[49152];
  signed char* Al = (signed char*)smem;            // 32 KB (2 x 16K)
  signed char* Bl = (signed char*)smem + 32768;    // 16 KB (2 x 8K)
  cg::grid_group grid = cg::this_grid();
  const int bid = blockIdx.x;
  const int wv = threadIdx.x >> 6;

  // stage 1: quantize hs + 4 weight matrices (7168 rows, 4 rows/block-job)
  for (int j = bid; j < 1792; j += GRID_N)
    quant_all_job(j * 4 + wv, a.hs, a.Wq, a.Wk, a.Wv, a.Wo, a.qx, a.sx,
                  a.qwq, a.qwk, a.qwv, a.qwo, a.swq, a.swk, a.swv, a.swo);
  grid.sync();

  // stage 2: QKV projections (1152 tile-jobs)
  for (int j = bid; j < 1152; j += GRID_N) {
    const int z = j / 384, rem = j - z * 384;
    const int by = rem >> 5, bx = rem & 31;
    if (z == 0)
      proj_body(1, bx, by, a.qx, a.sx, a.qwq, a.swq, a.bq, a.qqd, a.qqs,
                nullptr, nullptr, Al, Bl);
    else if (z == 1)
      proj_body(1, bx, by, a.qx, a.sx, a.qwk, a.swk, a.bk, a.qkd, a.qks,
                nullptr, nullptr, Al, Bl);
    else
      proj_body(2, bx, by, a.qx, a.sx, a.qwv, a.swv, a.bv, nullptr, nullptr,
                a.vt2, nullptr, Al, Bl);
  }
  grid.sync();

  // stage 3: attention (1536 jobs, exactly 3 per block)
  {
    _Float16* PhT0 = (_Float16*)smem;
    _Float16* PhT1 = PhT0 + 16 * PSTR;               // ends at 33280 B
    float* red_maxp  = (float*)(smem + 33280);       // 512 B
    float* red_sump  = (float*)(smem + 33792);       // 512 B
    float* red_amaxp = (float*)(smem + 34304);       // 512 B
    float* psap      = (float*)(smem + 34816);       // 128 B
    float4* pt4      = (float4*)(smem + 34944);      // 192 B
    if (threadIdx.x < 12)
      pt4[threadIdx.x] = make_float4(a.pc.b[threadIdx.x], a.pc.b[threadIdx.x + 1],
                                     a.pc.m[threadIdx.x], a.pc.c[threadIdx.x]);
    for (int j = bid; j < 1536; j += GRID_N) {
      const int bx = j & 15, t = j >> 4, by = t % 12, bz = t / 12;
      attn_body(bx, by, bz, a.qqd, a.qqs, a.qkd, a.qks, a.vt2, a.ctx,
                PhT0, PhT1, red_maxp, red_sump, red_amaxp, psap, pt4);
    }
  }
  grid.sync();

  // stage 4: quantize ctx rows into qx/sx alias (4096 rows)
  for (int j = bid; j < 1024; j += GRID_N) {
    const int row = j * 4 + wv;
    quant_row_wave(a.ctx + (size_t)row * HID, a.qx + (size_t)row * HID,
                   a.sx + row);
  }
  grid.sync();

  // stage 5: output projection (384 jobs)
  for (int j = bid; j < 384; j += GRID_N) {
    const int by = j >> 5, bx = j & 31;
    proj_body(0, bx, by, a.qx, a.sx, a.qwo, a.swo, a.bo, nullptr, nullptr,
              nullptr, a.out, Al, Bl);
  }
}

// --------------------------------------------------------------------------
extern "C" void kernel_launch(void* const* d_in, const int* in_sizes, int n_in,
                              void* d_out, int out_size, void* d_ws, size_t ws_size,
                              hipStream_t stream) {
  (void)in_sizes; (void)n_in; (void)out_size; (void)ws_size;
  const float* hs = (const float*)d_in[0];
  const float* Wq = (const float*)d_in[1];
  const float* bq = (const float*)d_in[2];
  const float* Wk = (const float*)d_in[3];
  const float* bk = (const float*)d_in[4];
  const float* Wv = (const float*)d_in[5];
  const float* bv = (const float*)d_in[6];
  const float* Wo = (const float*)d_in[7];
  const float* bo = (const float*)d_in[8];
  float* out = (float*)d_out;

  char* ws = (char*)d_ws;
  size_t off = 0;
  auto alloc = [&](size_t bytes) -> char* {
    char* p = ws + off;
    off += (bytes + 255) & ~(size_t)255;
    return p;
  };
  signed char* qx  = (signed char*)alloc((size_t)R_TOT * HID);
  float*       sx  = (float*)alloc((size_t)R_TOT * 4);
  signed char* qwq = (signed char*)alloc((size_t)HID * HID);
  signed char* qwk = (signed char*)alloc((size_t)HID * HID);
  signed char* qwv = (signed char*)alloc((size_t)HID * HID);
  signed char* qwo = (signed char*)alloc((size_t)HID * HID);
  float*       swq = (float*)alloc((size_t)HID * 4);
  float*       swk = (float*)alloc((size_t)HID * 4);
  float*       swv = (float*)alloc((size_t)HID * 4);
  float*       swo = (float*)alloc((size_t)HID * 4);
  signed char* qqd = (signed char*)alloc((size_t)R_TOT * HID);
  float*       qqs = (float*)alloc((size_t)BATCH * NHEAD * SEQ * 4);
  signed char* qkd = (signed char*)alloc((size_t)R_TOT * HID);
  float*       qks = (float*)alloc((size_t)BATCH * NHEAD * SEQ * 4);
  float*       ctx = (float*)alloc((size_t)R_TOT * HID * 4);
  _Float16*    vt2 = (_Float16*)alloc((size_t)BATCH * NHEAD * HDIM * SEQ * 2);
  // alias: qx/sx are dead after the QKV projections
  signed char* qc  = qx;
  float*       scs = sx;

  MegaArgs ma;
  ma.hs = hs; ma.Wq = Wq; ma.bq = bq; ma.Wk = Wk; ma.bk = bk;
  ma.Wv = Wv; ma.bv = bv; ma.Wo = Wo; ma.bo = bo; ma.out = out;
  ma.qx = qx; ma.sx = sx;
  ma.qwq = qwq; ma.qwk = qwk; ma.qwv = qwv; ma.qwo = qwo;
  ma.swq = swq; ma.swk = swk; ma.swv = swv; ma.swo = swo;
  ma.qqd = qqd; ma.qqs = qqs; ma.qkd = qkd; ma.qks = qks;
  ma.ctx = ctx; ma.vt2 = vt2;
  ma.pc = g_pla;

  void* kargs[] = { (void*)&ma };
  hipError_t err = hipLaunchCooperativeKernel(
      reinterpret_cast<const void*>(&mega_kernel),
      dim3(GRID_N), dim3(256), kargs, 0, stream);
  if (err != hipSuccess) {
    (void)hipGetLastError();  // clear sticky error, fall back to 5 kernels
    quant_all<<<(R_TOT + 4 * HID) / 4, 256, 0, stream>>>(
        hs, Wq, Wk, Wv, Wo, qx, sx,
        qwq, qwk, qwv, qwo, swq, swk, swv, swo);
    proj_qkv<<<dim3(R_TOT / 128, HID / 64, 3), 256, 0, stream>>>(
        qx, sx, qwq, swq, bq, qqd, qqs,
        qwk, swk, bk, qkd, qks,
        qwv, swv, bv, vt2);
    attn_kernel<<<dim3(SEQ / 32, NHEAD, BATCH), 256, 0, stream>>>(
        qqd, qqs, qkd, qks, vt2, ctx, g_pla);
    quant_rows<<<R_TOT / 4, 256, 0, stream>>>(ctx, qc, scs);
    proj_out<<<dim3(R_TOT / 128, HID / 64), 256, 0, stream>>>(
        qc, scs, qwo, swo, bo, out);
  }
}

// Round 5
// 331.201 us; speedup vs baseline: 1.6623x; 1.1925x over previous
//
#include <hip/hip_runtime.h>
#include <hip/hip_cooperative_groups.h>
#include <cmath>

namespace cg = cooperative_groups;

#define R_TOT 4096   // B*S rows
#define HID   768
#define NHEAD 12
#define HDIM  64
#define SEQ   512
#define BATCH 8

typedef int   v4i  __attribute__((ext_vector_type(4)));
typedef float v4f  __attribute__((ext_vector_type(4)));
typedef _Float16 half8 __attribute__((ext_vector_type(8)));
typedef _Float16 half4v __attribute__((ext_vector_type(4)));

// Direct global->LDS DMA, 16B per lane. HW semantics (m104/m108): dest =
// readfirstlane(ldsptr) + lane*16 — pass the wave-uniform chunk base.
__device__ __forceinline__ void gl_lds16(const signed char* g, signed char* l) {
  __builtin_amdgcn_global_load_lds(
      (const __attribute__((address_space(1))) void*)g,
      (__attribute__((address_space(3))) void*)l, 16, 0, 0);
}

// ---------------- PLA coefficients (host, replicates np.polyfit in f64) ----
struct PlaConsts { float m[12]; float c[12]; float b[13]; };

static PlaConsts build_pla() {
  PlaConsts pc;
  const int NPTS = 1001;
  static double xs[NPTS], ys[NPTS];
  const double step = 10.0 / 1000.0;
  for (int j = 0; j < NPTS; ++j) xs[j] = (double)j * step + (-10.0);
  xs[NPTS - 1] = 0.0;
  for (int j = 0; j < NPTS; ++j) ys[j] = std::exp(xs[j]);
  double bnd[13];
  const double step2 = 10.0 / 12.0;
  for (int k = 0; k < 13; ++k) bnd[k] = (double)k * step2 + (-10.0);
  bnd[12] = 0.0;
  for (int i = 0; i < 12; ++i) {
    const double a = bnd[i], bb = bnd[i + 1];
    double sx = 0, sy = 0; int n = 0;
    for (int j = 0; j < NPTS; ++j)
      if (xs[j] >= a && xs[j] <= bb) { sx += xs[j]; sy += ys[j]; ++n; }
    const double xm = sx / n, ym = sy / n;
    double sxx = 0, sxy = 0;
    for (int j = 0; j < NPTS; ++j)
      if (xs[j] >= a && xs[j] <= bb) {
        const double dx = xs[j] - xm;
        sxx += dx * dx; sxy += dx * (ys[j] - ym);
      }
    const double m = sxy / sxx;
    pc.m[i] = (float)m;
    pc.c[i] = (float)(ym - m * xm);
  }
  for (int k = 0; k < 13; ++k) pc.b[k] = (float)bnd[k];
  return pc;
}
static const PlaConsts g_pla = build_pla();

// ---------------- per-row abs-max int8 quantization (768 cols) -------------
__device__ __forceinline__ void quant_row_wave(const float* __restrict__ x,
                                               signed char* __restrict__ qrow,
                                               float* __restrict__ srow) {
  const int lane = threadIdx.x & 63;
  const float4* x4 = (const float4*)x;
  const float4 a = x4[lane];
  const float4 b = x4[lane + 64];
  const float4 c = x4[lane + 128];
  float m = fmaxf(fmaxf(fabsf(a.x), fabsf(a.y)), fmaxf(fabsf(a.z), fabsf(a.w)));
  m = fmaxf(m, fmaxf(fmaxf(fabsf(b.x), fabsf(b.y)), fmaxf(fabsf(b.z), fabsf(b.w))));
  m = fmaxf(m, fmaxf(fmaxf(fabsf(c.x), fabsf(c.y)), fmaxf(fabsf(c.z), fabsf(c.w))));
  #pragma unroll
  for (int off = 32; off; off >>= 1) m = fmaxf(m, __shfl_xor(m, off));
  float s = m / 127.0f;
  if (s == 0.f) s = 1.f;
  auto qb = [&](float v) -> int {
    return ((int)fminf(fmaxf(rintf(v / s), -127.f), 127.f)) & 255;
  };
  const int p0 = qb(a.x) | (qb(a.y) << 8) | (qb(a.z) << 16) | (qb(a.w) << 24);
  const int p1 = qb(b.x) | (qb(b.y) << 8) | (qb(b.z) << 16) | (qb(b.w) << 24);
  const int p2 = qb(c.x) | (qb(c.y) << 8) | (qb(c.z) << 16) | (qb(c.w) << 24);
  int* q4 = (int*)qrow;
  q4[lane] = p0;
  q4[lane + 64] = p1;
  q4[lane + 128] = p2;
  if (lane == 0) *srow = s;
}

__device__ __forceinline__
void quant_all_job(int row, const float* hs, const float* w0, const float* w1,
                   const float* w2, const float* w3,
                   signed char* qx, float* sx,
                   signed char* q0, signed char* q1, signed char* q2,
                   signed char* q3,
                   float* s0, float* s1, float* s2, float* s3) {
  const float* src; signed char* qo; float* so; int r;
  if (row < R_TOT)             { src = hs; qo = qx; so = sx; r = row; }
  else if (row < R_TOT + 768)  { src = w0; qo = q0; so = s0; r = row - R_TOT; }
  else if (row < R_TOT + 1536) { src = w1; qo = q1; so = s1; r = row - R_TOT - 768; }
  else if (row < R_TOT + 2304) { src = w2; qo = q2; so = s2; r = row - R_TOT - 1536; }
  else                         { src = w3; qo = q3; so = s3; r = row - R_TOT - 2304; }
  quant_row_wave(src + (size_t)r * HID, qo + (size_t)r * HID, so + r);
}

__global__ __launch_bounds__(256)
void quant_rows(const float* __restrict__ src,
                signed char* __restrict__ qout, float* __restrict__ sout) {
  const int row = blockIdx.x * 4 + (threadIdx.x >> 6);
  quant_row_wave(src + (size_t)row * HID, qout + (size_t)row * HID, sout + row);
}

__global__ __launch_bounds__(256)
void quant_all(const float* hs, const float* w0, const float* w1,
               const float* w2, const float* w3,
               signed char* qx, float* sx,
               signed char* q0, signed char* q1, signed char* q2, signed char* q3,
               float* s0, float* s1, float* s2, float* s3) {
  const int row = blockIdx.x * 4 + (threadIdx.x >> 6);
  quant_all_job(row, hs, w0, w1, w2, w3, qx, sx, q0, q1, q2, q3, s0, s1, s2, s3);
}

// ---------------- int8 MFMA GEMM body: 128x64 tile, BK=128, double-buffered.
// Staging via global_load_lds width=16 with XOR swizzle (see earlier rounds).
// One barrier per k-iter; entry barrier protects LDS reuse across job-loop
// iterations. Bit-exact vs the 2-barrier version.
__device__ __forceinline__
void proj_stage(const signed char* __restrict__ qx,
                const signed char* __restrict__ qw,
                int row0, int col0, int k0,
                signed char* __restrict__ Ab, signed char* __restrict__ Bb,
                int w, int lr, int cg) {
  #pragma unroll
  for (int m = 0; m < 4; ++m) {
    const int ci = w * 4 + m;                       // A chunk 0..15
    gl_lds16(qx + (size_t)(row0 + ci * 8 + lr) * HID + k0 + cg * 16,
             Ab + ci * 1024);
  }
  #pragma unroll
  for (int m = 0; m < 2; ++m) {
    const int ci = w * 2 + m;                       // B chunk 0..7
    gl_lds16(qw + (size_t)(col0 + ci * 8 + lr) * HID + k0 + cg * 16,
             Bb + ci * 1024);
  }
}

__device__ __forceinline__
void proj_body(int mode, int bx, int by,
               const signed char* __restrict__ qx, const float* __restrict__ sx,
               const signed char* __restrict__ qw, const float* __restrict__ sw,
               const float* __restrict__ bias,
               signed char* __restrict__ qo, float* __restrict__ so,
               _Float16* __restrict__ vt, float* __restrict__ fo,
               signed char* Al, signed char* Bl) {
  const int tid = threadIdx.x;
  const int w = tid >> 6, lane = tid & 63;
  const int n = lane & 15, quad = lane >> 4;
  const int row0 = bx * 128, col0 = by * 64;
  const int lr = lane >> 3;          // row within 8-row chunk
  const int lc = lane & 7;           // col16 slot
  const int cg = lc ^ lr;            // swizzled global col16 to fetch
  v4i acc[2][4];
  #pragma unroll
  for (int s = 0; s < 2; ++s)
    #pragma unroll
    for (int j = 0; j < 4; ++j) acc[s][j] = (v4i){0, 0, 0, 0};

  __syncthreads();  // protect LDS reuse across job-loop iterations
  // prologue: stage k-tile 0 into buffer 0
  proj_stage(qx, qw, row0, col0, 0, Al, Bl, w, lr, cg);
  __syncthreads();

  #pragma unroll
  for (int it = 0; it < 6; ++it) {
    signed char* Ac = Al + (it & 1) * 16384;
    signed char* Bc = Bl + (it & 1) * 8192;
    if (it < 5)
      proj_stage(qx, qw, row0, col0, (it + 1) * 128,
                 Al + ((it & 1) ^ 1) * 16384, Bl + ((it & 1) ^ 1) * 8192,
                 w, lr, cg);
    #pragma unroll
    for (int ks4 = 0; ks4 < 8; ks4 += 4) {
      const int sw16 = ((quad + ks4) ^ (n & 7)) * 16;   // inverse swizzle
      const v4i af0 = *(const v4i*)&Ac[(w * 16 + n) * 128 + sw16];
      const v4i af1 = *(const v4i*)&Ac[(64 + w * 16 + n) * 128 + sw16];
      #pragma unroll
      for (int j = 0; j < 4; ++j) {
        const v4i bf = *(const v4i*)&Bc[(j * 16 + n) * 128 + sw16];
        acc[0][j] = __builtin_amdgcn_mfma_i32_16x16x64_i8(af0, bf, acc[0][j], 0, 0, 0);
        acc[1][j] = __builtin_amdgcn_mfma_i32_16x16x64_i8(af1, bf, acc[1][j], 0, 0, 0);
      }
    }
    if (it < 5) __syncthreads();
  }

  float swc4[4], bc4[4];
  #pragma unroll
  for (int j = 0; j < 4; ++j) {
    swc4[j] = sw[col0 + j * 16 + n];
    bc4[j] = bias[col0 + j * 16 + n];
  }
  #pragma unroll
  for (int s = 0; s < 2; ++s) {
    const int mrow = s * 64 + w * 16 + quad * 4;
    float sxr[4];
    #pragma unroll
    for (int r = 0; r < 4; ++r) sxr[r] = sx[row0 + mrow + r];
    float vals[4][4];  // [j][r]
    #pragma unroll
    for (int j = 0; j < 4; ++j)
      #pragma unroll
      for (int r = 0; r < 4; ++r)
        vals[j][r] = (float)acc[s][j][r] * (sxr[r] * swc4[j]) + bc4[j];
    if (mode == 1) {
      const int h = by;
      #pragma unroll
      for (int r = 0; r < 4; ++r) {
        float m = 0.f;
        #pragma unroll
        for (int j = 0; j < 4; ++j) m = fmaxf(m, fabsf(vals[j][r]));
        #pragma unroll
        for (int off = 1; off < 16; off <<= 1) m = fmaxf(m, __shfl_xor(m, off));
        float sq = m / 127.0f;
        if (sq == 0.f) sq = 1.f;
        const int grow = row0 + mrow + r;
        const int bidx = grow >> 9, sidx = grow & 511;
        const size_t rowidx = ((size_t)bidx * NHEAD + h) * SEQ + sidx;
        #pragma unroll
        for (int j = 0; j < 4; ++j) {
          float q = fminf(fmaxf(rintf(vals[j][r] / sq), -127.f), 127.f);
          qo[rowidx * HDIM + j * 16 + n] = (signed char)(int)q;
        }
        if (n == 0) so[rowidx] = sq;
      }
    } else if (mode == 2) {
      const int h = by;
      float srow[4];
      #pragma unroll
      for (int r = 0; r < 4; ++r) {
        float m = 0.f;
        #pragma unroll
        for (int j = 0; j < 4; ++j) m = fmaxf(m, fabsf(vals[j][r]));
        #pragma unroll
        for (int off = 1; off < 16; off <<= 1) m = fmaxf(m, __shfl_xor(m, off));
        float sq = m / 127.0f;
        if (sq == 0.f) sq = 1.f;
        srow[r] = sq;
      }
      const int grow0 = row0 + mrow;         // 4 consecutive k, same batch
      const int bidx = grow0 >> 9, sidx = grow0 & 511;
      const int kb = sidx >> 5, ko = sidx & 31;
      const size_t hbv = (size_t)bidx * NHEAD + h;
      #pragma unroll
      for (int j = 0; j < 4; ++j) {
        half4v hv;
        #pragma unroll
        for (int r = 0; r < 4; ++r) {
          float q = fminf(fmaxf(rintf(vals[j][r] / srow[r]), -127.f), 127.f);
          hv[r] = (_Float16)(q * srow[r]);
        }
        *(half4v*)(vt + ((hbv * 16 + kb) * 64 + j * 16 + n) * 32 + ko) = hv;
      }
    } else {
      #pragma unroll
      for (int r = 0; r < 4; ++r) {
        const size_t base = (size_t)(row0 + mrow + r) * HID + col0;
        #pragma unroll
        for (int j = 0; j < 4; ++j)
          fo[base + j * 16 + n] = vals[j][r];
      }
    }
  }
}

// standalone wrappers (fallback path) ---------------------------------------
__global__ __launch_bounds__(256)
void proj_qkv(const signed char* __restrict__ qx, const float* __restrict__ sx,
              const signed char* qwq, const float* swq, const float* bq,
              signed char* qqd, float* qqs,
              const signed char* qwk, const float* swk, const float* bk,
              signed char* qkd, float* qks,
              const signed char* qwv, const float* swv, const float* bv,
              _Float16* vt2) {
  __shared__ __align__(16) signed char Al[2 * 128 * 128];
  __shared__ __align__(16) signed char Bl[2 * 64 * 128];
  if (blockIdx.z == 0)
    proj_body(1, blockIdx.x, blockIdx.y, qx, sx, qwq, swq, bq, qqd, qqs, nullptr, nullptr, Al, Bl);
  else if (blockIdx.z == 1)
    proj_body(1, blockIdx.x, blockIdx.y, qx, sx, qwk, swk, bk, qkd, qks, nullptr, nullptr, Al, Bl);
  else
    proj_body(2, blockIdx.x, blockIdx.y, qx, sx, qwv, swv, bv, nullptr, nullptr, vt2, nullptr, Al, Bl);
}

__global__ __launch_bounds__(256)
void proj_out(const signed char* __restrict__ qx, const float* __restrict__ sx,
              const signed char* qw, const float* sw, const float* bias,
              float* fo) {
  __shared__ __align__(16) signed char Al[2 * 128 * 128];
  __shared__ __align__(16) signed char Bl[2 * 64 * 128];
  proj_body(0, blockIdx.x, blockIdx.y, qx, sx, qw, sw, bias, nullptr, nullptr, nullptr, fo, Al, Bl);
}

// ---------------- fused front: quant_all + proj_qkv (cooperative) ----------
// Grid 768 = proj_qkv's natural 3 blocks/CU (48KB LDS); launch_bounds(256,3)
// caps VGPR at ~170 — proj needs ~128, quant ~32, so no spills (r3 lesson:
// only attn exceeds 128; it is NOT in this kernel).
struct FrontArgs {
  const float *hs, *Wq, *bq, *Wk, *bk, *Wv, *bv, *Wo;
  signed char* qx; float* sx;
  signed char *qwq, *qwk, *qwv, *qwo;
  float *swq, *swk, *swv, *swo;
  signed char* qqd; float* qqs;
  signed char* qkd; float* qks;
  _Float16* vt2;
};

__global__ __launch_bounds__(256, 3)
void fused_front(FrontArgs a) {
  __shared__ __align__(16) signed char Al[2 * 128 * 128];
  __shared__ __align__(16) signed char Bl[2 * 64 * 128];
  cg::grid_group grid = cg::this_grid();
  const int bid = blockIdx.x;
  const int wv = threadIdx.x >> 6;

  // stage 1: quantize hs + 4 weight matrices (1792 jobs x 4 rows)
  for (int j = bid; j < 1792; j += 768)
    quant_all_job(j * 4 + wv, a.hs, a.Wq, a.Wk, a.Wv, a.Wo, a.qx, a.sx,
                  a.qwq, a.qwk, a.qwv, a.qwo, a.swq, a.swk, a.swv, a.swo);
  grid.sync();

  // stage 2: QKV projections (1152 tile-jobs, 1-2 per block)
  for (int j = bid; j < 1152; j += 768) {
    const int z = j / 384, rem = j - z * 384;
    const int by = rem >> 5, bx = rem & 31;
    if (z == 0)
      proj_body(1, bx, by, a.qx, a.sx, a.qwq, a.swq, a.bq, a.qqd, a.qqs,
                nullptr, nullptr, Al, Bl);
    else if (z == 1)
      proj_body(1, bx, by, a.qx, a.sx, a.qwk, a.swk, a.bk, a.qkd, a.qks,
                nullptr, nullptr, Al, Bl);
    else
      proj_body(2, bx, by, a.qx, a.sx, a.qwv, a.swv, a.bv, nullptr, nullptr,
                a.vt2, nullptr, Al, Bl);
  }
}

// ---------------- fused back: quant_rows + proj_out (cooperative) ----------
struct BackArgs {
  const float* ctx; signed char* qc; float* scs;
  const signed char* qwo; const float* swo; const float* bo;
  float* out;
};

__global__ __launch_bounds__(256, 2)
void fused_back(BackArgs a) {
  __shared__ __align__(16) signed char Al[2 * 128 * 128];
  __shared__ __align__(16) signed char Bl[2 * 64 * 128];
  cg::grid_group grid = cg::this_grid();
  const int bid = blockIdx.x;
  const int wv = threadIdx.x >> 6;

  // stage 1: quantize ctx (1024 jobs x 4 rows, 2 per block)
  for (int j = bid; j < 1024; j += 512) {
    const int row = j * 4 + wv;
    quant_row_wave(a.ctx + (size_t)row * HID, a.qc + (size_t)row * HID,
                   a.scs + row);
  }
  grid.sync();

  // stage 2: output projection (384 jobs, 0-1 per block)
  for (int j = bid; j < 384; j += 512) {
    const int by = j >> 5, bx = j & 31;
    proj_body(0, bx, by, a.qc, a.scs, a.qwo, a.swo, a.bo, nullptr, nullptr,
              nullptr, a.out, Al, Bl);
  }
}

// ---------------- attention helpers ---------------------------------------
// Softmax PLA lookup with split tables: bounds2[g]={b[g],b[g+1]} (b64 read),
// corrected index, then coeffs2[gn]={m,c} (b64 read). Same table values and
// identical fp ops as the float4 version -> bit-exact; avoids the compiler's
// unconditional second ds_read_b128 + 4x cndmask for the rare-fixup path.
__device__ __forceinline__
void softmax_exp_tile(float (&s)[8][4], float mx26,
                      const float2* __restrict__ bnd2,
                      const float2* __restrict__ mc2,
                      float& sum_out, float& amax_out) {
  float sum = 0.f, amax = 0.f;
  #pragma unroll
  for (int t = 0; t < 8; ++t) {
    #pragma unroll
    for (int r = 0; r < 4; ++r) {
      float sh = s[t][r] - mx26;              // == (s-mx)*2^26 exactly
      sh = fmaxf(sh, -671088640.0f);          // clamp at -10*2^26
      const float tq = rintf(sh);
      const float xc = tq * 1.4901161193847656e-08f;  // *2^-26 (exact)
      int g = (int)((xc + 10.0f) * 1.2f);     // >=0 since xc>=-10
      g = g > 11 ? 11 : g;
      const float2 bd = bnd2[g];
      int gn = g + ((xc >= bd.y) ? 1 : 0) - ((xc < bd.x) ? 1 : 0);
      gn = gn < 0 ? 0 : (gn > 11 ? 11 : gn);
      const float2 mc = mc2[gn];
      const float e = __fadd_rn(__fmul_rn(mc.x, xc), mc.y);
      s[t][r] = e;
      sum += e;
      amax = fmaxf(amax, fabsf(e));
    }
  }
  sum += __shfl_xor(sum, 16);
  sum += __shfl_xor(sum, 32);
  amax = fmaxf(amax, __shfl_xor(amax, 16));
  amax = fmaxf(amax, __shfl_xor(amax, 32));
  sum_out = sum; amax_out = amax;
}

__device__ __forceinline__
void quant_pack_tile(const float (&s)[8][4], float t127,
                     _Float16* __restrict__ phtrow, int w, int quad) {
  #pragma unroll
  for (int t = 0; t < 8; ++t) {
    half4v hq;
    #pragma unroll
    for (int r = 0; r < 4; ++r) {
      const float qf = fminf(fmaxf(rintf(s[t][r] * t127), -127.f), 127.f);
      hq[r] = (_Float16)qf;
    }
    *(half4v*)&phtrow[(t * 4 + w) * 16 + quad * 4] = hq;
  }
}

__device__ __forceinline__
v4f pv_tile(const _Float16* __restrict__ vbase, const _Float16* __restrict__ prow) {
  v4f acc = {0.f, 0.f, 0.f, 0.f};
  #pragma unroll
  for (int kt = 0; kt < 16; ++kt) {
    const half8 bf = *(const half8*)(vbase + kt * 2048);
    acc = __builtin_amdgcn_mfma_f32_16x16x32_f16(*(const half8*)(prow + kt * 32), bf, acc, 0, 0, 0);
  }
  return acc;
}

// ---------------- fused attention: dual-tile, overlapped phases ------------
// P1(both) | 2a(t0) | 2b(t0)+2a(t1) | PV(t0)+2b(t1) | PV(t1)  — 4 barriers.
#define PSTR 520  // PhT row stride in halves (16B-aligned rows)
__global__ __launch_bounds__(256)
void attn_kernel(const signed char* __restrict__ qq, const float* __restrict__ qss,
                 const signed char* __restrict__ qk, const float* __restrict__ kss,
                 const _Float16* __restrict__ vt2,
                 float* __restrict__ ctx, const PlaConsts pc) {
  __shared__ __align__(16) _Float16 PhT[2][16 * PSTR];
  __shared__ __align__(16) float red_max[2][16][4];
  __shared__ __align__(16) float red_sum[2][16][4];
  __shared__ __align__(16) float red_amax[2][16][4];
  __shared__ __align__(16) float psa[2][16];
  __shared__ __align__(16) float2 bnd2[12];
  __shared__ __align__(16) float2 mc2[12];

  const int tid = threadIdx.x;
  const int q0 = blockIdx.x * 32;
  const int hh = blockIdx.y, bz = blockIdx.z;
  const size_t hb = (size_t)bz * NHEAD + hh;
  const signed char* qqh = qq + (hb * SEQ + q0) * HDIM;
  const signed char* qkh = qk + hb * SEQ * HDIM;
  const float* ksp = kss + hb * SEQ;

  if (tid < 12) {
    bnd2[tid] = make_float2(pc.b[tid], pc.b[tid + 1]);
    mc2[tid] = make_float2(pc.m[tid], pc.c[tid]);
  }

  const int w = tid >> 6, lane = tid & 63;
  const int n = lane & 15, quad = lane >> 4;

  // ---- Phase 1: S^T via i8 MFMA (A=K rows, B=Q rows), two q-tiles ----
  float s26[2][8][4];
  {
    const v4i qf0 = *(const v4i*)(qqh + (size_t)n * HDIM + quad * 16);
    const v4i qf1 = *(const v4i*)(qqh + (size_t)(16 + n) * HDIM + quad * 16);
    const float qs0 = (qss[hb * SEQ + q0 + n] * 0.125f) * 67108864.0f;
    const float qs1 = (qss[hb * SEQ + q0 + 16 + n] * 0.125f) * 67108864.0f;
    float vmax0 = -3.0e38f, vmax1 = -3.0e38f;
    #pragma unroll
    for (int t = 0; t < 8; ++t) {
      const int kc0 = (t * 4 + w) * 16;
      const v4i kfrag = *(const v4i*)(qkh + (size_t)(kc0 + n) * HDIM + quad * 16);
      const float4 ks4 = *(const float4*)(ksp + kc0 + quad * 4);
      v4i zero = {};
      const v4i a0 = __builtin_amdgcn_mfma_i32_16x16x64_i8(kfrag, qf0, zero, 0, 0, 0);
      const v4i a1 = __builtin_amdgcn_mfma_i32_16x16x64_i8(kfrag, qf1, zero, 0, 0, 0);
      const float ks[4] = {ks4.x, ks4.y, ks4.z, ks4.w};
      #pragma unroll
      for (int r = 0; r < 4; ++r) {
        const float v0 = (float)a0[r] * (qs0 * ks[r]);
        const float v1 = (float)a1[r] * (qs1 * ks[r]);
        s26[0][t][r] = v0; vmax0 = fmaxf(vmax0, v0);
        s26[1][t][r] = v1; vmax1 = fmaxf(vmax1, v1);
      }
    }
    vmax0 = fmaxf(vmax0, __shfl_xor(vmax0, 16));
    vmax0 = fmaxf(vmax0, __shfl_xor(vmax0, 32));
    vmax1 = fmaxf(vmax1, __shfl_xor(vmax1, 16));
    vmax1 = fmaxf(vmax1, __shfl_xor(vmax1, 32));
    if (quad == 0) { red_max[0][n][w] = vmax0; red_max[1][n][w] = vmax1; }
  }
  __syncthreads();  // bar1

  // ---- Phase B: 2a(t0) ----
  {
    const float4 rm = *(const float4*)&red_max[0][n][0];
    const float mx26 = fmaxf(fmaxf(rm.x, rm.y), fmaxf(rm.z, rm.w));
    float sum, amax;
    softmax_exp_tile(s26[0], mx26, bnd2, mc2, sum, amax);
    if (quad == 0) { red_sum[0][n][w] = sum; red_amax[0][n][w] = amax; }
  }
  __syncthreads();  // bar2

  // ---- Phase C: 2b(t0) -> PhT[0]  +  2a(t1) ----
  {
    const float4 rs = *(const float4*)&red_sum[0][n][0];
    const float4 ra = *(const float4*)&red_amax[0][n][0];
    float denom = (rs.x + rs.y) + (rs.z + rs.w);
    denom = __fadd_rn(denom, 1e-9f);
    const float rden = 1.0f / denom;
    const float am = fmaxf(fmaxf(ra.x, ra.y), fmaxf(ra.z, ra.w));
    float ps = (am * rden) / 127.0f;
    if (ps == 0.f) ps = 1.f;
    if (w == 0 && quad == 0) psa[0][n] = ps;
    const float t127 = 127.0f / am;
    quant_pack_tile(s26[0], t127, &PhT[0][n * PSTR], w, quad);

    const float4 rm = *(const float4*)&red_max[1][n][0];
    const float mx26 = fmaxf(fmaxf(rm.x, rm.y), fmaxf(rm.z, rm.w));
    float sum, amax;
    softmax_exp_tile(s26[1], mx26, bnd2, mc2, sum, amax);
    if (quad == 0) { red_sum[1][n][w] = sum; red_amax[1][n][w] = amax; }
  }
  __syncthreads();  // bar3

  const _Float16* vbase = vt2 + ((size_t)hb * 16 * 64 + (w * 16 + n)) * 32 + quad * 8;

  // ---- Phase D: PV(t0)  +  2b(t1) -> PhT[1] ----
  {
    const v4f acc0 = pv_tile(vbase, &PhT[0][n * PSTR + quad * 8]);

    const float4 rs = *(const float4*)&red_sum[1][n][0];
    const float4 ra = *(const float4*)&red_amax[1][n][0];
    float denom = (rs.x + rs.y) + (rs.z + rs.w);
    denom = __fadd_rn(denom, 1e-9f);
    const float rden = 1.0f / denom;
    const float am = fmaxf(fmaxf(ra.x, ra.y), fmaxf(ra.z, ra.w));
    float ps = (am * rden) / 127.0f;
    if (ps == 0.f) ps = 1.f;
    if (w == 0 && quad == 0) psa[1][n] = ps;
    const float t127 = 127.0f / am;
    quant_pack_tile(s26[1], t127, &PhT[1][n * PSTR], w, quad);

    #pragma unroll
    for (int r = 0; r < 4; ++r) {
      const int row = quad * 4 + r;
      ctx[((size_t)bz * SEQ + q0 + row) * HID + (size_t)hh * HDIM + w * 16 + n] =
          acc0[r] * psa[0][row];
    }
  }
  __syncthreads();  // bar4

  // ---- Phase E: PV(t1) ----
  {
    const v4f acc1 = pv_tile(vbase, &PhT[1][n * PSTR + quad * 8]);
    #pragma unroll
    for (int r = 0; r < 4; ++r) {
      const int row = quad * 4 + r;
      ctx[((size_t)bz * SEQ + q0 + 16 + row) * HID + (size_t)hh * HDIM + w * 16 + n] =
          acc1[r] * psa[1][row];
    }
  }
}

// --------------------------------------------------------------------------
extern "C" void kernel_launch(void* const* d_in, const int* in_sizes, int n_in,
                              void* d_out, int out_size, void* d_ws, size_t ws_size,
                              hipStream_t stream) {
  (void)in_sizes; (void)n_in; (void)out_size; (void)ws_size;
  const float* hs = (const float*)d_in[0];
  const float* Wq = (const float*)d_in[1];
  const float* bq = (const float*)d_in[2];
  const float* Wk = (const float*)d_in[3];
  const float* bk = (const float*)d_in[4];
  const float* Wv = (const float*)d_in[5];
  const float* bv = (const float*)d_in[6];
  const float* Wo = (const float*)d_in[7];
  const float* bo = (const float*)d_in[8];
  float* out = (float*)d_out;

  char* ws = (char*)d_ws;
  size_t off = 0;
  auto alloc = [&](size_t bytes) -> char* {
    char* p = ws + off;
    off += (bytes + 255) & ~(size_t)255;
    return p;
  };
  signed char* qx  = (signed char*)alloc((size_t)R_TOT * HID);
  float*       sx  = (float*)alloc((size_t)R_TOT * 4);
  signed char* qwq = (signed char*)alloc((size_t)HID * HID);
  signed char* qwk = (signed char*)alloc((size_t)HID * HID);
  signed char* qwv = (signed char*)alloc((size_t)HID * HID);
  signed char* qwo = (signed char*)alloc((size_t)HID * HID);
  float*       swq = (float*)alloc((size_t)HID * 4);
  float*       swk = (float*)alloc((size_t)HID * 4);
  float*       swv = (float*)alloc((size_t)HID * 4);
  float*       swo = (float*)alloc((size_t)HID * 4);
  signed char* qqd = (signed char*)alloc((size_t)R_TOT * HID);
  float*       qqs = (float*)alloc((size_t)BATCH * NHEAD * SEQ * 4);
  signed char* qkd = (signed char*)alloc((size_t)R_TOT * HID);
  float*       qks = (float*)alloc((size_t)BATCH * NHEAD * SEQ * 4);
  float*       ctx = (float*)alloc((size_t)R_TOT * HID * 4);
  _Float16*    vt2 = (_Float16*)alloc((size_t)BATCH * NHEAD * HDIM * SEQ * 2);
  // alias: qx/sx are dead after the QKV projections
  signed char* qc  = qx;
  float*       scs = sx;

  FrontArgs fa;
  fa.hs = hs; fa.Wq = Wq; fa.bq = bq; fa.Wk = Wk; fa.bk = bk;
  fa.Wv = Wv; fa.bv = bv; fa.Wo = Wo;
  fa.qx = qx; fa.sx = sx;
  fa.qwq = qwq; fa.qwk = qwk; fa.qwv = qwv; fa.qwo = qwo;
  fa.swq = swq; fa.swk = swk; fa.swv = swv; fa.swo = swo;
  fa.qqd = qqd; fa.qqs = qqs; fa.qkd = qkd; fa.qks = qks;
  fa.vt2 = vt2;

  void* fargs[] = { (void*)&fa };
  hipError_t e1 = hipLaunchCooperativeKernel(
      reinterpret_cast<const void*>(&fused_front),
      dim3(768), dim3(256), fargs, 0, stream);
  if (e1 != hipSuccess) {
    (void)hipGetLastError();
    quant_all<<<(R_TOT + 4 * HID) / 4, 256, 0, stream>>>(
        hs, Wq, Wk, Wv, Wo, qx, sx,
        qwq, qwk, qwv, qwo, swq, swk, swv, swo);
    proj_qkv<<<dim3(R_TOT / 128, HID / 64, 3), 256, 0, stream>>>(
        qx, sx, qwq, swq, bq, qqd, qqs,
        qwk, swk, bk, qkd, qks,
        qwv, swv, bv, vt2);
  }

  attn_kernel<<<dim3(SEQ / 32, NHEAD, BATCH), 256, 0, stream>>>(
      qqd, qqs, qkd, qks, vt2, ctx, g_pla);

  BackArgs ba;
  ba.ctx = ctx; ba.qc = qc; ba.scs = scs;
  ba.qwo = qwo; ba.swo = swo; ba.bo = bo; ba.out = out;

  void* bargs[] = { (void*)&ba };
  hipError_t e2 = hipLaunchCooperativeKernel(
      reinterpret_cast<const void*>(&fused_back),
      dim3(512), dim3(256), bargs, 0, stream);
  if (e2 != hipSuccess) {
    (void)hipGetLastError();
    quant_rows<<<R_TOT / 4, 256, 0, stream>>>(ctx, qc, scs);
    proj_out<<<dim3(R_TOT / 128, HID / 64), 256, 0, stream>>>(
        qc, scs, qwo, swo, bo, out);
  }
}

// Round 6
// 149.744 us; speedup vs baseline: 3.6766x; 2.2118x over previous
//
#include <hip/hip_runtime.h>
#include <cmath>

#define R_TOT 4096   // B*S rows
#define HID   768
#define NHEAD 12
#define HDIM  64
#define SEQ   512
#define BATCH 8

typedef int   v4i  __attribute__((ext_vector_type(4)));
typedef float v4f  __attribute__((ext_vector_type(4)));
typedef _Float16 half8 __attribute__((ext_vector_type(8)));
typedef _Float16 half4v __attribute__((ext_vector_type(4)));

// Direct global->LDS DMA, 16B per lane. HW semantics (m104/m108): dest =
// readfirstlane(ldsptr) + lane*16 — pass the wave-uniform chunk base.
__device__ __forceinline__ void gl_lds16(const signed char* g, signed char* l) {
  __builtin_amdgcn_global_load_lds(
      (const __attribute__((address_space(1))) void*)g,
      (__attribute__((address_space(3))) void*)l, 16, 0, 0);
}

// ---------------- PLA coefficients (host, replicates np.polyfit in f64) ----
struct PlaConsts { float m[12]; float c[12]; float b[13]; };

static PlaConsts build_pla() {
  PlaConsts pc;
  const int NPTS = 1001;
  static double xs[NPTS], ys[NPTS];
  const double step = 10.0 / 1000.0;
  for (int j = 0; j < NPTS; ++j) xs[j] = (double)j * step + (-10.0);
  xs[NPTS - 1] = 0.0;
  for (int j = 0; j < NPTS; ++j) ys[j] = std::exp(xs[j]);
  double bnd[13];
  const double step2 = 10.0 / 12.0;
  for (int k = 0; k < 13; ++k) bnd[k] = (double)k * step2 + (-10.0);
  bnd[12] = 0.0;
  for (int i = 0; i < 12; ++i) {
    const double a = bnd[i], bb = bnd[i + 1];
    double sx = 0, sy = 0; int n = 0;
    for (int j = 0; j < NPTS; ++j)
      if (xs[j] >= a && xs[j] <= bb) { sx += xs[j]; sy += ys[j]; ++n; }
    const double xm = sx / n, ym = sy / n;
    double sxx = 0, sxy = 0;
    for (int j = 0; j < NPTS; ++j)
      if (xs[j] >= a && xs[j] <= bb) {
        const double dx = xs[j] - xm;
        sxx += dx * dx; sxy += dx * (ys[j] - ym);
      }
    const double m = sxy / sxx;
    pc.m[i] = (float)m;
    pc.c[i] = (float)(ym - m * xm);
  }
  for (int k = 0; k < 13; ++k) pc.b[k] = (float)bnd[k];
  return pc;
}
static const PlaConsts g_pla = build_pla();

// ---------------- per-row abs-max int8 quantization (768 cols) -------------
// One wave per row: float4 loads (12 f32/lane), 64-lane butterfly max,
// packed 4x int8 stores. No LDS, no barriers.
__device__ __forceinline__ void quant_row_wave(const float* __restrict__ x,
                                               signed char* __restrict__ qrow,
                                               float* __restrict__ srow) {
  const int lane = threadIdx.x & 63;
  const float4* x4 = (const float4*)x;
  const float4 a = x4[lane];
  const float4 b = x4[lane + 64];
  const float4 c = x4[lane + 128];
  float m = fmaxf(fmaxf(fabsf(a.x), fabsf(a.y)), fmaxf(fabsf(a.z), fabsf(a.w)));
  m = fmaxf(m, fmaxf(fmaxf(fabsf(b.x), fabsf(b.y)), fmaxf(fabsf(b.z), fabsf(b.w))));
  m = fmaxf(m, fmaxf(fmaxf(fabsf(c.x), fabsf(c.y)), fmaxf(fabsf(c.z), fabsf(c.w))));
  #pragma unroll
  for (int off = 32; off; off >>= 1) m = fmaxf(m, __shfl_xor(m, off));
  float s = m / 127.0f;
  if (s == 0.f) s = 1.f;
  auto qb = [&](float v) -> int {
    return ((int)fminf(fmaxf(rintf(v / s), -127.f), 127.f)) & 255;
  };
  const int p0 = qb(a.x) | (qb(a.y) << 8) | (qb(a.z) << 16) | (qb(a.w) << 24);
  const int p1 = qb(b.x) | (qb(b.y) << 8) | (qb(b.z) << 16) | (qb(b.w) << 24);
  const int p2 = qb(c.x) | (qb(c.y) << 8) | (qb(c.z) << 16) | (qb(c.w) << 24);
  int* q4 = (int*)qrow;
  q4[lane] = p0;
  q4[lane + 64] = p1;
  q4[lane + 128] = p2;
  if (lane == 0) *srow = s;
}

__global__ __launch_bounds__(256)
void quant_rows(const float* __restrict__ src,
                signed char* __restrict__ qout, float* __restrict__ sout) {
  const int row = blockIdx.x * 4 + (threadIdx.x >> 6);
  quant_row_wave(src + (size_t)row * HID, qout + (size_t)row * HID, sout + row);
}

__global__ __launch_bounds__(256)
void quant_all(const float* hs, const float* w0, const float* w1,
               const float* w2, const float* w3,
               signed char* qx, float* sx,
               signed char* q0, signed char* q1, signed char* q2, signed char* q3,
               float* s0, float* s1, float* s2, float* s3) {
  const int row = blockIdx.x * 4 + (threadIdx.x >> 6);
  const float* src; signed char* qo; float* so; int r;
  if (row < R_TOT)             { src = hs; qo = qx; so = sx; r = row; }
  else if (row < R_TOT + 768)  { src = w0; qo = q0; so = s0; r = row - R_TOT; }
  else if (row < R_TOT + 1536) { src = w1; qo = q1; so = s1; r = row - R_TOT - 768; }
  else if (row < R_TOT + 2304) { src = w2; qo = q2; so = s2; r = row - R_TOT - 1536; }
  else                         { src = w3; qo = q3; so = s3; r = row - R_TOT - 2304; }
  quant_row_wave(src + (size_t)r * HID, qo + (size_t)r * HID, so + r);
}

// ---------------- int8 MFMA GEMM body: 128x64 tile, BK=128 -----------------
// r0 structure (session-best 150.9): 24 KB LDS (higher occupancy than the
// 48 KB dbuf variant), 2 barriers per k-iter, gl_lds16 staging with XOR
// swizzle. Bit-exact numerics across all session variants.
// mode 0: fp32 dense out; mode 1: per-head int8 (bhsd) + scales;
// mode 2: V path -> fp16 k-chunked transposed vt2[hb][k>>5][d][k&31]
__device__ __forceinline__
void proj_body(int mode,
               const signed char* __restrict__ qx, const float* __restrict__ sx,
               const signed char* __restrict__ qw, const float* __restrict__ sw,
               const float* __restrict__ bias,
               signed char* __restrict__ qo, float* __restrict__ so,
               _Float16* __restrict__ vt, float* __restrict__ fo,
               signed char* Al, signed char* Bl) {
  const int tid = threadIdx.x;
  const int w = tid >> 6, lane = tid & 63;
  const int n = lane & 15, quad = lane >> 4;
  const int row0 = blockIdx.x * 128, col0 = blockIdx.y * 64;
  const int lr = lane >> 3;          // row within 8-row chunk
  const int lc = lane & 7;           // col16 slot
  const int cg = lc ^ lr;            // swizzled global col16 to fetch
  v4i acc[2][4];
  #pragma unroll
  for (int s = 0; s < 2; ++s)
    #pragma unroll
    for (int j = 0; j < 4; ++j) acc[s][j] = (v4i){0, 0, 0, 0};
  for (int k0 = 0; k0 < HID; k0 += 128) {
    if (k0) __syncthreads();
    #pragma unroll
    for (int m = 0; m < 4; ++m) {
      const int ci = w * 4 + m;                     // A chunk 0..15
      gl_lds16(qx + (size_t)(row0 + ci * 8 + lr) * HID + k0 + cg * 16,
               Al + ci * 1024);
    }
    #pragma unroll
    for (int m = 0; m < 2; ++m) {
      const int ci = w * 2 + m;                     // B chunk 0..7
      gl_lds16(qw + (size_t)(col0 + ci * 8 + lr) * HID + k0 + cg * 16,
               Bl + ci * 1024);
    }
    __syncthreads();
    #pragma unroll
    for (int ks4 = 0; ks4 < 8; ks4 += 4) {
      const int sw16 = ((quad + ks4) ^ (n & 7)) * 16;   // inverse swizzle
      const v4i af0 = *(const v4i*)&Al[(w * 16 + n) * 128 + sw16];
      const v4i af1 = *(const v4i*)&Al[(64 + w * 16 + n) * 128 + sw16];
      #pragma unroll
      for (int j = 0; j < 4; ++j) {
        const v4i bf = *(const v4i*)&Bl[(j * 16 + n) * 128 + sw16];
        acc[0][j] = __builtin_amdgcn_mfma_i32_16x16x64_i8(af0, bf, acc[0][j], 0, 0, 0);
        acc[1][j] = __builtin_amdgcn_mfma_i32_16x16x64_i8(af1, bf, acc[1][j], 0, 0, 0);
      }
    }
  }
  float swc4[4], bc4[4];
  #pragma unroll
  for (int j = 0; j < 4; ++j) {
    swc4[j] = sw[col0 + j * 16 + n];
    bc4[j] = bias[col0 + j * 16 + n];
  }
  #pragma unroll
  for (int s = 0; s < 2; ++s) {
    const int mrow = s * 64 + w * 16 + quad * 4;
    float sxr[4];
    #pragma unroll
    for (int r = 0; r < 4; ++r) sxr[r] = sx[row0 + mrow + r];
    float vals[4][4];  // [j][r]
    #pragma unroll
    for (int j = 0; j < 4; ++j)
      #pragma unroll
      for (int r = 0; r < 4; ++r)
        vals[j][r] = (float)acc[s][j][r] * (sxr[r] * swc4[j]) + bc4[j];
    if (mode == 1) {
      const int h = blockIdx.y;
      #pragma unroll
      for (int r = 0; r < 4; ++r) {
        float m = 0.f;
        #pragma unroll
        for (int j = 0; j < 4; ++j) m = fmaxf(m, fabsf(vals[j][r]));
        #pragma unroll
        for (int off = 1; off < 16; off <<= 1) m = fmaxf(m, __shfl_xor(m, off));
        float sq = m / 127.0f;
        if (sq == 0.f) sq = 1.f;
        const int grow = row0 + mrow + r;
        const int bidx = grow >> 9, sidx = grow & 511;
        const size_t rowidx = ((size_t)bidx * NHEAD + h) * SEQ + sidx;
        #pragma unroll
        for (int j = 0; j < 4; ++j) {
          float q = fminf(fmaxf(rintf(vals[j][r] / sq), -127.f), 127.f);
          qo[rowidx * HDIM + j * 16 + n] = (signed char)(int)q;
        }
        if (n == 0) so[rowidx] = sq;
      }
    } else if (mode == 2) {
      const int h = blockIdx.y;
      float srow[4];
      #pragma unroll
      for (int r = 0; r < 4; ++r) {
        float m = 0.f;
        #pragma unroll
        for (int j = 0; j < 4; ++j) m = fmaxf(m, fabsf(vals[j][r]));
        #pragma unroll
        for (int off = 1; off < 16; off <<= 1) m = fmaxf(m, __shfl_xor(m, off));
        float sq = m / 127.0f;
        if (sq == 0.f) sq = 1.f;
        srow[r] = sq;
      }
      const int grow0 = row0 + mrow;         // 4 consecutive k, same batch
      const int bidx = grow0 >> 9, sidx = grow0 & 511;
      const int kb = sidx >> 5, ko = sidx & 31;
      const size_t hbv = (size_t)bidx * NHEAD + h;
      #pragma unroll
      for (int j = 0; j < 4; ++j) {
        half4v hv;
        #pragma unroll
        for (int r = 0; r < 4; ++r) {
          float q = fminf(fmaxf(rintf(vals[j][r] / srow[r]), -127.f), 127.f);
          hv[r] = (_Float16)(q * srow[r]);
        }
        *(half4v*)(vt + ((hbv * 16 + kb) * 64 + j * 16 + n) * 32 + ko) = hv;
      }
    } else {
      #pragma unroll
      for (int r = 0; r < 4; ++r) {
        const size_t base = (size_t)(row0 + mrow + r) * HID + col0;
        #pragma unroll
        for (int j = 0; j < 4; ++j)
          fo[base + j * 16 + n] = vals[j][r];
      }
    }
  }
}

// fused Q/K/V projections: blockIdx.z selects weight/output
__global__ __launch_bounds__(256)
void proj_qkv(const signed char* __restrict__ qx, const float* __restrict__ sx,
              const signed char* qwq, const float* swq, const float* bq,
              signed char* qqd, float* qqs,
              const signed char* qwk, const float* swk, const float* bk,
              signed char* qkd, float* qks,
              const signed char* qwv, const float* swv, const float* bv,
              _Float16* vt2) {
  __shared__ __align__(16) signed char Al[128 * 128];
  __shared__ __align__(16) signed char Bl[64 * 128];
  if (blockIdx.z == 0)
    proj_body(1, qx, sx, qwq, swq, bq, qqd, qqs, nullptr, nullptr, Al, Bl);
  else if (blockIdx.z == 1)
    proj_body(1, qx, sx, qwk, swk, bk, qkd, qks, nullptr, nullptr, Al, Bl);
  else
    proj_body(2, qx, sx, qwv, swv, bv, nullptr, nullptr, vt2, nullptr, Al, Bl);
}

__global__ __launch_bounds__(256)
void proj_out(const signed char* __restrict__ qx, const float* __restrict__ sx,
              const signed char* qw, const float* sw, const float* bias,
              float* fo) {
  __shared__ __align__(16) signed char Al[128 * 128];
  __shared__ __align__(16) signed char Bl[64 * 128];
  proj_body(0, qx, sx, qw, sw, bias, nullptr, nullptr, nullptr, fo, Al, Bl);
}

// ---------------- attention helpers ---------------------------------------
// Softmax PLA lookup with split tables: bnd2[g]={b[g],b[g+1]} (b64 read),
// corrected index, then mc2[gn]={m,c} (b64 read). Same table values and
// identical fp ops as the float4 version -> bit-exact; avoids the
// unconditional second b128 read + cndmask chain of the fixup path.
__device__ __forceinline__
void softmax_exp_tile(float (&s)[8][4], float mx26,
                      const float2* __restrict__ bnd2,
                      const float2* __restrict__ mc2,
                      float& sum_out, float& amax_out) {
  float sum = 0.f, amax = 0.f;
  #pragma unroll
  for (int t = 0; t < 8; ++t) {
    #pragma unroll
    for (int r = 0; r < 4; ++r) {
      float sh = s[t][r] - mx26;              // == (s-mx)*2^26 exactly
      sh = fmaxf(sh, -671088640.0f);          // clamp at -10*2^26
      const float tq = rintf(sh);
      const float xc = tq * 1.4901161193847656e-08f;  // *2^-26 (exact)
      int g = (int)((xc + 10.0f) * 1.2f);     // >=0 since xc>=-10
      g = g > 11 ? 11 : g;
      const float2 bd = bnd2[g];
      int gn = g + ((xc >= bd.y) ? 1 : 0) - ((xc < bd.x) ? 1 : 0);
      gn = gn < 0 ? 0 : (gn > 11 ? 11 : gn);
      const float2 mc = mc2[gn];
      const float e = __fadd_rn(__fmul_rn(mc.x, xc), mc.y);
      s[t][r] = e;
      sum += e;
      amax = fmaxf(amax, fabsf(e));
    }
  }
  sum += __shfl_xor(sum, 16);
  sum += __shfl_xor(sum, 32);
  amax = fmaxf(amax, __shfl_xor(amax, 16));
  amax = fmaxf(amax, __shfl_xor(amax, 32));
  sum_out = sum; amax_out = amax;
}

__device__ __forceinline__
void quant_pack_tile(const float (&s)[8][4], float t127,
                     _Float16* __restrict__ phtrow, int w, int quad) {
  #pragma unroll
  for (int t = 0; t < 8; ++t) {
    half4v hq;
    #pragma unroll
    for (int r = 0; r < 4; ++r) {
      const float qf = fminf(fmaxf(rintf(s[t][r] * t127), -127.f), 127.f);
      hq[r] = (_Float16)qf;
    }
    *(half4v*)&phtrow[(t * 4 + w) * 16 + quad * 4] = hq;
  }
}

__device__ __forceinline__
v4f pv_tile(const _Float16* __restrict__ vbase, const _Float16* __restrict__ prow) {
  v4f acc = {0.f, 0.f, 0.f, 0.f};
  #pragma unroll
  for (int kt = 0; kt < 16; ++kt) {
    const half8 bf = *(const half8*)(vbase + kt * 2048);
    acc = __builtin_amdgcn_mfma_f32_16x16x32_f16(*(const half8*)(prow + kt * 32), bf, acc, 0, 0, 0);
  }
  return acc;
}

// ---------------- fused attention: dual-tile, overlapped phases ------------
// P1(both) | 2a(t0) | 2b(t0)+2a(t1) | PV(t0)+2b(t1) | PV(t1)  — 4 barriers.
#define PSTR 520  // PhT row stride in halves (16B-aligned rows)
__global__ __launch_bounds__(256)
void attn_kernel(const signed char* __restrict__ qq, const float* __restrict__ qss,
                 const signed char* __restrict__ qk, const float* __restrict__ kss,
                 const _Float16* __restrict__ vt2,
                 float* __restrict__ ctx, const PlaConsts pc) {
  __shared__ __align__(16) _Float16 PhT[2][16 * PSTR];
  __shared__ __align__(16) float red_max[2][16][4];
  __shared__ __align__(16) float red_sum[2][16][4];
  __shared__ __align__(16) float red_amax[2][16][4];
  __shared__ float psa[2][16];
  __shared__ __align__(16) float2 bnd2[12];
  __shared__ __align__(16) float2 mc2[12];

  const int tid = threadIdx.x;
  const int q0 = blockIdx.x * 32;
  const int hh = blockIdx.y, bz = blockIdx.z;
  const size_t hb = (size_t)bz * NHEAD + hh;
  const signed char* qqh = qq + (hb * SEQ + q0) * HDIM;
  const signed char* qkh = qk + hb * SEQ * HDIM;
  const float* ksp = kss + hb * SEQ;

  if (tid < 12) {
    bnd2[tid] = make_float2(pc.b[tid], pc.b[tid + 1]);
    mc2[tid] = make_float2(pc.m[tid], pc.c[tid]);
  }

  const int w = tid >> 6, lane = tid & 63;
  const int n = lane & 15, quad = lane >> 4;

  // ---- Phase 1: S^T via i8 MFMA (A=K rows, B=Q rows), two q-tiles ----
  float s26[2][8][4];
  {
    const v4i qf0 = *(const v4i*)(qqh + (size_t)n * HDIM + quad * 16);
    const v4i qf1 = *(const v4i*)(qqh + (size_t)(16 + n) * HDIM + quad * 16);
    const float qs0 = (qss[hb * SEQ + q0 + n] * 0.125f) * 67108864.0f;
    const float qs1 = (qss[hb * SEQ + q0 + 16 + n] * 0.125f) * 67108864.0f;
    float vmax0 = -3.0e38f, vmax1 = -3.0e38f;
    #pragma unroll
    for (int t = 0; t < 8; ++t) {
      const int kc0 = (t * 4 + w) * 16;
      const v4i kfrag = *(const v4i*)(qkh + (size_t)(kc0 + n) * HDIM + quad * 16);
      const float4 ks4 = *(const float4*)(ksp + kc0 + quad * 4);
      v4i zero = {};
      const v4i a0 = __builtin_amdgcn_mfma_i32_16x16x64_i8(kfrag, qf0, zero, 0, 0, 0);
      const v4i a1 = __builtin_amdgcn_mfma_i32_16x16x64_i8(kfrag, qf1, zero, 0, 0, 0);
      const float ks[4] = {ks4.x, ks4.y, ks4.z, ks4.w};
      #pragma unroll
      for (int r = 0; r < 4; ++r) {
        const float v0 = (float)a0[r] * (qs0 * ks[r]);
        const float v1 = (float)a1[r] * (qs1 * ks[r]);
        s26[0][t][r] = v0; vmax0 = fmaxf(vmax0, v0);
        s26[1][t][r] = v1; vmax1 = fmaxf(vmax1, v1);
      }
    }
    vmax0 = fmaxf(vmax0, __shfl_xor(vmax0, 16));
    vmax0 = fmaxf(vmax0, __shfl_xor(vmax0, 32));
    vmax1 = fmaxf(vmax1, __shfl_xor(vmax1, 16));
    vmax1 = fmaxf(vmax1, __shfl_xor(vmax1, 32));
    if (quad == 0) { red_max[0][n][w] = vmax0; red_max[1][n][w] = vmax1; }
  }
  __syncthreads();  // bar1

  // ---- Phase B: 2a(t0) ----
  {
    const float4 rm = *(const float4*)&red_max[0][n][0];
    const float mx26 = fmaxf(fmaxf(rm.x, rm.y), fmaxf(rm.z, rm.w));
    float sum, amax;
    softmax_exp_tile(s26[0], mx26, bnd2, mc2, sum, amax);
    if (quad == 0) { red_sum[0][n][w] = sum; red_amax[0][n][w] = amax; }
  }
  __syncthreads();  // bar2

  // ---- Phase C: 2b(t0) -> PhT[0]  +  2a(t1) ----
  {
    const float4 rs = *(const float4*)&red_sum[0][n][0];
    const float4 ra = *(const float4*)&red_amax[0][n][0];
    float denom = (rs.x + rs.y) + (rs.z + rs.w);
    denom = __fadd_rn(denom, 1e-9f);
    const float rden = 1.0f / denom;
    const float am = fmaxf(fmaxf(ra.x, ra.y), fmaxf(ra.z, ra.w));
    float ps = (am * rden) / 127.0f;
    if (ps == 0.f) ps = 1.f;
    if (w == 0 && quad == 0) psa[0][n] = ps;
    const float t127 = 127.0f / am;
    quant_pack_tile(s26[0], t127, &PhT[0][n * PSTR], w, quad);

    const float4 rm = *(const float4*)&red_max[1][n][0];
    const float mx26 = fmaxf(fmaxf(rm.x, rm.y), fmaxf(rm.z, rm.w));
    float sum, amax;
    softmax_exp_tile(s26[1], mx26, bnd2, mc2, sum, amax);
    if (quad == 0) { red_sum[1][n][w] = sum; red_amax[1][n][w] = amax; }
  }
  __syncthreads();  // bar3

  const _Float16* vbase = vt2 + ((size_t)hb * 16 * 64 + (w * 16 + n)) * 32 + quad * 8;

  // ---- Phase D: PV(t0)  +  2b(t1) -> PhT[1] ----
  {
    const v4f acc0 = pv_tile(vbase, &PhT[0][n * PSTR + quad * 8]);

    const float4 rs = *(const float4*)&red_sum[1][n][0];
    const float4 ra = *(const float4*)&red_amax[1][n][0];
    float denom = (rs.x + rs.y) + (rs.z + rs.w);
    denom = __fadd_rn(denom, 1e-9f);
    const float rden = 1.0f / denom;
    const float am = fmaxf(fmaxf(ra.x, ra.y), fmaxf(ra.z, ra.w));
    float ps = (am * rden) / 127.0f;
    if (ps == 0.f) ps = 1.f;
    if (w == 0 && quad == 0) psa[1][n] = ps;
    const float t127 = 127.0f / am;
    quant_pack_tile(s26[1], t127, &PhT[1][n * PSTR], w, quad);

    #pragma unroll
    for (int r = 0; r < 4; ++r) {
      const int row = quad * 4 + r;
      ctx[((size_t)bz * SEQ + q0 + row) * HID + (size_t)hh * HDIM + w * 16 + n] =
          acc0[r] * psa[0][row];
    }
  }
  __syncthreads();  // bar4

  // ---- Phase E: PV(t1) ----
  {
    const v4f acc1 = pv_tile(vbase, &PhT[1][n * PSTR + quad * 8]);
    #pragma unroll
    for (int r = 0; r < 4; ++r) {
      const int row = quad * 4 + r;
      ctx[((size_t)bz * SEQ + q0 + 16 + row) * HID + (size_t)hh * HDIM + w * 16 + n] =
          acc1[r] * psa[1][row];
    }
  }
}

// --------------------------------------------------------------------------
extern "C" void kernel_launch(void* const* d_in, const int* in_sizes, int n_in,
                              void* d_out, int out_size, void* d_ws, size_t ws_size,
                              hipStream_t stream) {
  (void)in_sizes; (void)n_in; (void)out_size; (void)ws_size;
  const float* hs = (const float*)d_in[0];
  const float* Wq = (const float*)d_in[1];
  const float* bq = (const float*)d_in[2];
  const float* Wk = (const float*)d_in[3];
  const float* bk = (const float*)d_in[4];
  const float* Wv = (const float*)d_in[5];
  const float* bv = (const float*)d_in[6];
  const float* Wo = (const float*)d_in[7];
  const float* bo = (const float*)d_in[8];
  float* out = (float*)d_out;

  char* ws = (char*)d_ws;
  size_t off = 0;
  auto alloc = [&](size_t bytes) -> char* {
    char* p = ws + off;
    off += (bytes + 255) & ~(size_t)255;
    return p;
  };
  signed char* qx  = (signed char*)alloc((size_t)R_TOT * HID);
  float*       sx  = (float*)alloc((size_t)R_TOT * 4);
  signed char* qwq = (signed char*)alloc((size_t)HID * HID);
  signed char* qwk = (signed char*)alloc((size_t)HID * HID);
  signed char* qwv = (signed char*)alloc((size_t)HID * HID);
  signed char* qwo = (signed char*)alloc((size_t)HID * HID);
  float*       swq = (float*)alloc((size_t)HID * 4);
  float*       swk = (float*)alloc((size_t)HID * 4);
  float*       swv = (float*)alloc((size_t)HID * 4);
  float*       swo = (float*)alloc((size_t)HID * 4);
  signed char* qqd = (signed char*)alloc((size_t)R_TOT * HID);
  float*       qqs = (float*)alloc((size_t)BATCH * NHEAD * SEQ * 4);
  signed char* qkd = (signed char*)alloc((size_t)R_TOT * HID);
  float*       qks = (float*)alloc((size_t)BATCH * NHEAD * SEQ * 4);
  float*       ctx = (float*)alloc((size_t)R_TOT * HID * 4);
  _Float16*    vt2 = (_Float16*)alloc((size_t)BATCH * NHEAD * HDIM * SEQ * 2);
  // alias: qx/sx are dead after the QKV projections
  signed char* qc  = qx;
  float*       scs = sx;

  quant_all<<<(R_TOT + 4 * HID) / 4, 256, 0, stream>>>(
      hs, Wq, Wk, Wv, Wo, qx, sx,
      qwq, qwk, qwv, qwo, swq, swk, swv, swo);

  proj_qkv<<<dim3(R_TOT / 128, HID / 64, 3), 256, 0, stream>>>(
      qx, sx, qwq, swq, bq, qqd, qqs,
      qwk, swk, bk, qkd, qks,
      qwv, swv, bv, vt2);

  attn_kernel<<<dim3(SEQ / 32, NHEAD, BATCH), 256, 0, stream>>>(
      qqd, qqs, qkd, qks, vt2, ctx, g_pla);

  quant_rows<<<R_TOT / 4, 256, 0, stream>>>(ctx, qc, scs);
  proj_out<<<dim3(R_TOT / 128, HID / 64), 256, 0, stream>>>(
      qc, scs, qwo, swo, bo, out);
}